// Round 4
// baseline (381.315 us; speedup 1.0000x reference)
//
#include <hip/hip_runtime.h>
#include <math.h>

#define MPTS 2048
#define NBATCH 8
#define NT 32            // MPTS / 64 candidates per lane
#define KMAX 64
#define BLKA 1024        // kernelA block size (16 waves)

typedef unsigned short u16;
typedef unsigned long long u64;

// Fused count pass: counts how many d3 <= t3 and d6 <= t6 across the wave.
// Two independent ballot chains interleaved for ILP. Wave-uniform results.
static __device__ __forceinline__ void count2(const float* d3, float t3,
                                              const float* d6, float t6,
                                              int& c3, int& c6) {
  int a = 0, b = 0;
#pragma unroll
  for (int k = 0; k < NT; ++k) {
    a += __popcll(__ballot(d3[k] <= t3));
    b += __popcll(__ballot(d6[k] <= t6));
  }
  c3 = a; c6 = b;
}

// Bracket update with Illinois side-halving. Returns true iff exact hit.
static __device__ __forceinline__ bool upd(float m, int n, float& lo, float& hi,
                                           float& clo, float& chi, int& side) {
  if (n >= 64) {
    hi = m; chi = (float)n;
    if (side == -1) clo = 64.5f - 0.5f * (64.5f - clo);   // Illinois pull
    side = -1;
    return n == 64;                                        // exact only
  } else {
    lo = m; clo = (float)n;
    if (side == 1) chi = 64.5f + 0.5f * (chi - 64.5f);
    side = 1;
    return false;
  }
}

static __device__ __forceinline__ float interp(float lo, float hi,
                                               float clo, float chi) {
  float f = (64.5f - clo) / (chi - clo);
  f = fminf(fmaxf(f, 0.03f), 0.97f);
  return lo + f * (hi - lo);
}

// Dual EXACT top-64 threshold search: t s.t. |{d <= t}| == 64, or rmax2 if
// fewer than 64 within. Power-law seed + Illinois regula falsi + bisection
// tail (convergence guarantee). Both searches fused for ILP.
static __device__ __forceinline__ void kth_dual(const float* d3, const float* d6,
                                                float& t3o, float& t6o) {
  const float R3 = 0.16f, R6 = 0.2025f;
  int c3, c6;
  count2(d3, R3, d6, R6, c3, c6);
  float lo3 = 0.f, hi3 = R3, lo6 = 0.f, hi6 = R6;
  float clo3 = 0.f, chi3 = (float)c3, clo6 = 0.f, chi6 = (float)c6;
  bool done3 = (c3 <= 64), done6 = (c6 <= 64);
  int side3 = 0, side6 = 0;

  if (!(done3 && done6)) {   // power-law seed: count ~ C * t^{D/2}
    float m3 = hi3, m6 = hi6;
    if (!done3) m3 = hi3 * exp2f(0.6666667f * log2f(64.5f / chi3));
    if (!done6) m6 = hi6 * exp2f(0.3333333f * log2f(64.5f / chi6));
    int n3, n6;
    count2(d3, m3, d6, m6, n3, n6);
    if (!done3) done3 = upd(m3, n3, lo3, hi3, clo3, chi3, side3);
    if (!done6) done6 = upd(m6, n6, lo6, hi6, clo6, chi6, side6);
  }

  for (int it = 0; it < 14 && !(done3 && done6); ++it) {   // Illinois
    const float m3 = done3 ? hi3 : interp(lo3, hi3, clo3, chi3);
    const float m6 = done6 ? hi6 : interp(lo6, hi6, clo6, chi6);
    int n3, n6;
    count2(d3, m3, d6, m6, n3, n6);
    if (!done3) done3 = upd(m3, n3, lo3, hi3, clo3, chi3, side3);
    if (!done6) done6 = upd(m6, n6, lo6, hi6, clo6, chi6, side6);
  }
  for (int it = 0; it < 8 && !(done3 && done6); ++it) {    // bisection tail
    const float m3 = done3 ? hi3 : 0.5f * (lo3 + hi3);
    const float m6 = done6 ? hi6 : 0.5f * (lo6 + hi6);
    int n3, n6;
    count2(d3, m3, d6, m6, n3, n6);
    if (!done3) done3 = upd(m3, n3, lo3, hi3, clo3, chi3, side3);
    if (!done6) done6 = upd(m6, n6, lo6, hi6, clo6, chi6, side6);
  }
  t3o = hi3; t6o = hi6;
}

// Kernel A: per point -> x_centers (3 scales, interleaved float4) + tau3 +
// (fast path) compacted 3D neighbor list: 64 x u16 {idx[10:0] | class[12:11]},
// slot 0 = self, class 3 = invalid.
template <bool COMPACT>
__global__ __launch_bounds__(BLKA) void kernelA(
    const float* __restrict__ x, const float* __restrict__ pos,
    float4* __restrict__ xci, float* __restrict__ tau3, u16* __restrict__ nbr) {
  const int wid  = (blockIdx.x * BLKA + threadIdx.x) >> 6;  // global point id
  const int lane = threadIdx.x & 63;
  const int b = wid >> 11;
  const int i = wid & (MPTS - 1);
  const float* posb = pos + b * MPTS * 3;
  const float* xb   = x   + b * MPTS * 3;

  const float pix = posb[3*i+0], piy = posb[3*i+1], piz = posb[3*i+2];
  const float xix = xb[3*i+0],   xiy = xb[3*i+1],   xiz = xb[3*i+2];

  float d3a[NT], d6a[NT];
#pragma unroll
  for (int k = 0; k < NT; ++k) {
    const int j = k * 64 + lane;
    const float dx = posb[3*j+0] - pix;
    const float dy = posb[3*j+1] - piy;
    const float dz = posb[3*j+2] - piz;
    const float a3 = dx*dx + dy*dy + dz*dz;
    const float ex = xb[3*j+0] - xix;
    const float ey = xb[3*j+1] - xiy;
    const float ez = xb[3*j+2] - xiz;
    d3a[k] = a3;
    d6a[k] = a3 + ex*ex + ey*ey + ez*ez;
  }

  float t3, t6;
  kth_dual(d3a, d6a, t3, t6);

  const float thr0 = fminf(0.0225f, t6);
  const float thr1 = fminf(0.0625f, t6);

  float vals[12];  // {sx,sy,sz,n} x 3 scales
#pragma unroll
  for (int v = 0; v < 12; ++v) vals[v] = 0.f;

  int base = 1;    // slot 0 reserved for self
#pragma unroll
  for (int k = 0; k < NT; ++k) {
    const int j = k * 64 + lane;
    if (d6a[k] <= t6) {
      const float xjx = xb[3*j+0], xjy = xb[3*j+1], xjz = xb[3*j+2];
      vals[8] += xjx; vals[9] += xjy; vals[10] += xjz; vals[11] += 1.f;
      if (d6a[k] <= thr1) {
        vals[4] += xjx; vals[5] += xjy; vals[6] += xjz; vals[7] += 1.f;
        if (d6a[k] <= thr0) {
          vals[0] += xjx; vals[1] += xjy; vals[2] += xjz; vals[3] += 1.f;
        }
      }
    }
    if (COMPACT) {
      const bool sel = (d3a[k] <= t3) && (j != i);
      const u64 mask = __ballot(sel);
      const int rank = __builtin_amdgcn_mbcnt_hi(
          (unsigned)(mask >> 32), __builtin_amdgcn_mbcnt_lo((unsigned)mask, 0));
      const int slot = base + rank;
      if (sel && slot < KMAX) {
        const int cl = (d3a[k] > 0.01f) + (d3a[k] > 0.04f);
        nbr[(size_t)wid * KMAX + slot] = (u16)(j | (cl << 11));
      }
      base += __popcll(mask);
    }
  }

#pragma unroll
  for (int v = 0; v < 12; ++v)
#pragma unroll
    for (int off = 32; off > 0; off >>= 1)
      vals[v] += __shfl_xor(vals[v], off, 64);

  if (COMPACT) {
    const int total = (base < KMAX) ? base : KMAX;
    if (lane >= total) nbr[(size_t)wid * KMAX + lane] = (u16)(3u << 11);
  }

  if (lane == 0) {
#pragma unroll
    for (int s = 0; s < 3; ++s) {
      const float inv = 1.f / vals[4*s + 3];
      xci[(size_t)wid * 3 + s] =
          make_float4(vals[4*s] * inv, vals[4*s+1] * inv, vals[4*s+2] * inv, 0.f);
    }
    tau3[wid] = t3;
    if (COMPACT) nbr[(size_t)wid * KMAX + 0] = (u16)i;   // self, class 0
  }
}

// Kernel B (fast): one wave per point, lane L handles neighbor slot L.
__global__ __launch_bounds__(256) void kernelB_fast(
    const float4* __restrict__ xci, const float* __restrict__ wlin,
    const float* __restrict__ blin, const u16* __restrict__ nbr,
    float* __restrict__ out) {
  const int wid  = (blockIdx.x * 256 + threadIdx.x) >> 6;  // global point id
  const int lane = threadIdx.x & 63;
  const int pbase = wid & ~(MPTS - 1);                     // batch start

  const u16 e = nbr[(size_t)wid * KMAX + lane];
  const int cl = e >> 11;
  const int gj = pbase + (e & (MPTS - 1));

  const float4 ci0 = xci[(size_t)wid*3 + 0];
  const float4 ci1 = xci[(size_t)wid*3 + 1];
  const float4 ci2 = xci[(size_t)wid*3 + 2];

  float s0 = 0.f, s1 = 0.f, s2 = 0.f, n0 = 0.f, n1 = 0.f, n2 = 0.f;
  if (cl <= 2) {
    const float4 cj2 = xci[(size_t)gj*3 + 2];
    float ux = ci2.x - cj2.x, uy = ci2.y - cj2.y, uz = ci2.z - cj2.z;
    s2 = sqrtf(fmaxf(ux*ux + uy*uy + uz*uz, 1e-12f)); n2 = 1.f;
    if (cl <= 1) {
      const float4 cj1 = xci[(size_t)gj*3 + 1];
      ux = ci1.x - cj1.x; uy = ci1.y - cj1.y; uz = ci1.z - cj1.z;
      s1 = sqrtf(fmaxf(ux*ux + uy*uy + uz*uz, 1e-12f)); n1 = 1.f;
      if (cl == 0) {
        const float4 cj0 = xci[(size_t)gj*3 + 0];
        ux = ci0.x - cj0.x; uy = ci0.y - cj0.y; uz = ci0.z - cj0.z;
        s0 = sqrtf(fmaxf(ux*ux + uy*uy + uz*uz, 1e-12f)); n0 = 1.f;
      }
    }
  }

  float vals[6] = {s0, s1, s2, n0, n1, n2};
#pragma unroll
  for (int v = 0; v < 6; ++v)
#pragma unroll
    for (int off = 32; off > 0; off >>= 1)
      vals[v] += __shfl_xor(vals[v], off, 64);

  if (lane == 0) {
    const float msg0 = vals[0] / vals[3];
    const float msg1 = vals[1] / vals[4];
    const float msg2 = vals[2] / vals[5];
    const float z = wlin[0]*msg0 + wlin[1]*msg1 + wlin[2]*msg2 + blin[0];
    out[wid] = 1.f / (1.f + expf(-z));
  }
}

// Kernel B (fallback, ws too small): full scan with tau3 thresholds.
__global__ __launch_bounds__(256) void kernelB_slow(
    const float* __restrict__ pos, const float* __restrict__ wlin,
    const float* __restrict__ blin, const float4* __restrict__ xci,
    const float* __restrict__ tau3, float* __restrict__ out) {
  const int wid  = (blockIdx.x * 256 + threadIdx.x) >> 6;
  const int lane = threadIdx.x & 63;
  const int b = wid >> 11;
  const int i = wid & (MPTS - 1);
  const float* posb = pos + b * MPTS * 3;
  const int pbase = b * MPTS;

  const float pix = posb[3*i+0], piy = posb[3*i+1], piz = posb[3*i+2];
  const float t3 = tau3[wid];
  const float thr0 = fminf(0.01f, t3);
  const float thr1 = fminf(0.04f, t3);

  const float4 ci0 = xci[(size_t)wid*3 + 0];
  const float4 ci1 = xci[(size_t)wid*3 + 1];
  const float4 ci2 = xci[(size_t)wid*3 + 2];

  float s0=0.f, s1=0.f, s2=0.f, n0=0.f, n1=0.f, n2=0.f;
  for (int k = 0; k < NT; ++k) {
    const int j = k * 64 + lane;
    const float dx = posb[3*j+0] - pix;
    const float dy = posb[3*j+1] - piy;
    const float dz = posb[3*j+2] - piz;
    const float a3 = dx*dx + dy*dy + dz*dz;
    if (a3 <= t3) {
      const float4 cj2 = xci[(size_t)(pbase + j)*3 + 2];
      float ux = ci2.x-cj2.x, uy = ci2.y-cj2.y, uz = ci2.z-cj2.z;
      s2 += sqrtf(fmaxf(ux*ux+uy*uy+uz*uz, 1e-12f)); n2 += 1.f;
      if (a3 <= thr1) {
        const float4 cj1 = xci[(size_t)(pbase + j)*3 + 1];
        ux = ci1.x-cj1.x; uy = ci1.y-cj1.y; uz = ci1.z-cj1.z;
        s1 += sqrtf(fmaxf(ux*ux+uy*uy+uz*uz, 1e-12f)); n1 += 1.f;
        if (a3 <= thr0) {
          const float4 cj0 = xci[(size_t)(pbase + j)*3 + 0];
          ux = ci0.x-cj0.x; uy = ci0.y-cj0.y; uz = ci0.z-cj0.z;
          s0 += sqrtf(fmaxf(ux*ux+uy*uy+uz*uz, 1e-12f)); n0 += 1.f;
        }
      }
    }
  }

  float vals[6] = {s0, s1, s2, n0, n1, n2};
#pragma unroll
  for (int v = 0; v < 6; ++v)
#pragma unroll
    for (int off = 32; off > 0; off >>= 1)
      vals[v] += __shfl_xor(vals[v], off, 64);

  if (lane == 0) {
    const float msg0 = vals[0] / vals[3];
    const float msg1 = vals[1] / vals[4];
    const float msg2 = vals[2] / vals[5];
    const float z = wlin[0]*msg0 + wlin[1]*msg1 + wlin[2]*msg2 + blin[0];
    out[wid] = 1.f / (1.f + expf(-z));
  }
}

extern "C" void kernel_launch(void* const* d_in, const int* in_sizes, int n_in,
                              void* d_out, int out_size, void* d_ws, size_t ws_size,
                              hipStream_t stream) {
  (void)in_sizes; (void)n_in; (void)out_size;
  const float* x    = (const float*)d_in[0];   // [8,2048,3]
  const float* pos  = (const float*)d_in[1];   // [8,2048,3]
  const float* wlin = (const float*)d_in[2];   // [1,3]
  const float* blin = (const float*)d_in[3];   // [1]
  float* out = (float*)d_out;

  const size_t npts = (size_t)NBATCH * MPTS;
  const size_t xci_bytes = npts * 3 * sizeof(float4);   // 786,432
  const size_t tau_bytes = npts * sizeof(float);        //  65,536
  const size_t nbr_bytes = npts * KMAX * sizeof(u16);   // 2,097,152
  float4* xci = (float4*)d_ws;
  float* tau3 = (float*)((char*)d_ws + xci_bytes);
  u16* nbr    = (u16*)((char*)d_ws + xci_bytes + tau_bytes);
  const bool fast = ws_size >= xci_bytes + tau_bytes + nbr_bytes;

  const int nblocksA = (int)(npts * 64 / BLKA);   // 16 waves (points) per block
  const int nblocksB = (int)(npts * 64 / 256);
  if (fast) {
    kernelA<true><<<nblocksA, BLKA, 0, stream>>>(x, pos, xci, tau3, nbr);
    kernelB_fast<<<nblocksB, 256, 0, stream>>>(xci, wlin, blin, nbr, out);
  } else {
    kernelA<false><<<nblocksA, BLKA, 0, stream>>>(x, pos, xci, tau3, nbr);
    kernelB_slow<<<nblocksB, 256, 0, stream>>>(pos, wlin, blin, xci, tau3, out);
  }
}

// Round 5
// 196.906 us; speedup vs baseline: 1.9365x; 1.9365x over previous
//
#include <hip/hip_runtime.h>
#include <math.h>

#define MPTS 2048
#define NBATCH 8
#define NT 32            // MPTS / 64 candidates per lane
#define KMAX 64

typedef unsigned short u16;
typedef unsigned long long u64;

// Fused quad count pass: counts for two thresholds on each of d3/d6.
// Four independent ballot chains interleaved for ILP. Wave-uniform results.
static __device__ __forceinline__ void count4(
    const float* d3, float a3, float b3,
    const float* d6, float a6, float b6,
    int& ca3, int& cb3, int& ca6, int& cb6) {
  int p = 0, q = 0, r = 0, s = 0;
#pragma unroll
  for (int k = 0; k < NT; ++k) {
    p += __popcll(__ballot(d3[k] <= a3));
    q += __popcll(__ballot(d3[k] <= b3));
    r += __popcll(__ballot(d6[k] <= a6));
    s += __popcll(__ballot(d6[k] <= b6));
  }
  ca3 = p; cb3 = q; ca6 = r; cb6 = s;
}

// Dual-probe bracket update (m1 <= m2, counts n1 <= n2). Returns exact-hit.
static __device__ __forceinline__ bool upd2(float m1, float m2, int n1, int n2,
                                            float& lo, float& hi,
                                            float& clo, float& chi) {
  if (n1 >= 64) { hi = m1; chi = (float)n1; return n1 == 64; }
  if (n2 >= 64) { lo = m1; clo = (float)n1; hi = m2; chi = (float)n2; return n2 == 64; }
  lo = m2; clo = (float)n2; return false;
}

// Secant probe within bracket.
static __device__ __forceinline__ float interp(float lo, float hi,
                                               float clo, float chi) {
  float f = (64.5f - clo) / (chi - clo);
  f = fminf(fmaxf(f, 0.02f), 0.98f);
  return lo + f * (hi - lo);
}

// Dual EXACT top-64 threshold search: t s.t. |{d <= t}| == 64, or rmax2 if
// fewer than 64 lie within. Pass 1 probes {static seed, rmax2}; then each
// pass probes {secant, midpoint} per metric — bracket shrinks >=2x/pass and
// secant typically hits count==64 exactly in 2-3 passes.
static __device__ __forceinline__ void kth_dual(const float* d3, const float* d6,
                                                float& t3o, float& t6o) {
  const float R3 = 0.16f, R6 = 0.2025f;     // r^2 caps
  const float S3 = 0.042f, S6 = 0.088f;     // static power-law seeds

  int cs3, cr3, cs6, cr6;
  count4(d3, S3, R3, d6, S6, R6, cs3, cr3, cs6, cr6);

  float lo3, hi3, clo3, chi3, lo6, hi6, clo6, chi6;
  bool done3, done6;

  if (cr3 <= 64) { lo3 = hi3 = R3; clo3 = chi3 = (float)cr3; done3 = true; }
  else if (cs3 >= 64) { lo3 = 0.f; clo3 = 0.f; hi3 = S3; chi3 = (float)cs3; done3 = (cs3 == 64); }
  else { lo3 = S3; clo3 = (float)cs3; hi3 = R3; chi3 = (float)cr3; done3 = false; }

  if (cr6 <= 64) { lo6 = hi6 = R6; clo6 = chi6 = (float)cr6; done6 = true; }
  else if (cs6 >= 64) { lo6 = 0.f; clo6 = 0.f; hi6 = S6; chi6 = (float)cs6; done6 = (cs6 == 64); }
  else { lo6 = S6; clo6 = (float)cs6; hi6 = R6; chi6 = (float)cr6; done6 = false; }

  for (int it = 0; it < 12 && !(done3 && done6); ++it) {
    float a3 = hi3, b3 = hi3, a6 = hi6, b6 = hi6;
    if (!done3) {
      const float ms = interp(lo3, hi3, clo3, chi3);
      const float mm = 0.5f * (lo3 + hi3);
      a3 = fminf(ms, mm); b3 = fmaxf(ms, mm);
    }
    if (!done6) {
      const float ms = interp(lo6, hi6, clo6, chi6);
      const float mm = 0.5f * (lo6 + hi6);
      a6 = fminf(ms, mm); b6 = fmaxf(ms, mm);
    }
    int n1_3, n2_3, n1_6, n2_6;
    count4(d3, a3, b3, d6, a6, b6, n1_3, n2_3, n1_6, n2_6);
    if (!done3) done3 = upd2(a3, b3, n1_3, n2_3, lo3, hi3, clo3, chi3);
    if (!done6) done6 = upd2(a6, b6, n1_6, n2_6, lo6, hi6, clo6, chi6);
  }
  t3o = hi3; t6o = hi6;
}

// Kernel A: per point -> x_centers (3 scales, interleaved float4) + tau3 +
// compacted 3D neighbor list: 64 x u16 {idx[10:0] | class[12:11]},
// slot 0 = self, class 3 = invalid.
template <bool COMPACT>
__global__ __launch_bounds__(256) void kernelA(
    const float* __restrict__ x, const float* __restrict__ pos,
    float4* __restrict__ xci, float* __restrict__ tau3, u16* __restrict__ nbr) {
  const int wid  = (blockIdx.x * 256 + threadIdx.x) >> 6;   // global point id
  const int lane = threadIdx.x & 63;
  const int b = wid >> 11;
  const int i = wid & (MPTS - 1);
  const float* posb = pos + b * MPTS * 3;
  const float* xb   = x   + b * MPTS * 3;

  const float pix = posb[3*i+0], piy = posb[3*i+1], piz = posb[3*i+2];
  const float xix = xb[3*i+0],   xiy = xb[3*i+1],   xiz = xb[3*i+2];

  float d3a[NT], d6a[NT];
#pragma unroll
  for (int k = 0; k < NT; ++k) {
    const int j = k * 64 + lane;
    const float dx = posb[3*j+0] - pix;
    const float dy = posb[3*j+1] - piy;
    const float dz = posb[3*j+2] - piz;
    const float a3 = dx*dx + dy*dy + dz*dz;
    const float ex = xb[3*j+0] - xix;
    const float ey = xb[3*j+1] - xiy;
    const float ez = xb[3*j+2] - xiz;
    d3a[k] = a3;
    d6a[k] = a3 + ex*ex + ey*ey + ez*ez;
  }

  float t3, t6;
  kth_dual(d3a, d6a, t3, t6);

  const float thr0 = fminf(0.0225f, t6);
  const float thr1 = fminf(0.0625f, t6);

  float vals[12];  // {sx,sy,sz,n} x 3 scales
#pragma unroll
  for (int v = 0; v < 12; ++v) vals[v] = 0.f;

  int base = 1;    // slot 0 reserved for self
#pragma unroll
  for (int k = 0; k < NT; ++k) {
    const int j = k * 64 + lane;
    if (d6a[k] <= t6) {
      const float xjx = xb[3*j+0], xjy = xb[3*j+1], xjz = xb[3*j+2];
      vals[8] += xjx; vals[9] += xjy; vals[10] += xjz; vals[11] += 1.f;
      if (d6a[k] <= thr1) {
        vals[4] += xjx; vals[5] += xjy; vals[6] += xjz; vals[7] += 1.f;
        if (d6a[k] <= thr0) {
          vals[0] += xjx; vals[1] += xjy; vals[2] += xjz; vals[3] += 1.f;
        }
      }
    }
    if (COMPACT) {
      const bool sel = (d3a[k] <= t3) && (j != i);
      const u64 mask = __ballot(sel);
      const int rank = __builtin_amdgcn_mbcnt_hi(
          (unsigned)(mask >> 32), __builtin_amdgcn_mbcnt_lo((unsigned)mask, 0));
      const int slot = base + rank;
      if (sel && slot < KMAX) {
        const int cl = (d3a[k] > 0.01f) + (d3a[k] > 0.04f);
        nbr[(size_t)wid * KMAX + slot] = (u16)(j | (cl << 11));
      }
      base += __popcll(mask);
    }
  }

#pragma unroll
  for (int v = 0; v < 12; ++v)
#pragma unroll
    for (int off = 32; off > 0; off >>= 1)
      vals[v] += __shfl_xor(vals[v], off, 64);

  if (COMPACT) {
    const int total = (base < KMAX) ? base : KMAX;
    if (lane >= total) nbr[(size_t)wid * KMAX + lane] = (u16)(3u << 11);
  }

  if (lane == 0) {
#pragma unroll
    for (int s = 0; s < 3; ++s) {
      const float inv = 1.f / vals[4*s + 3];
      xci[(size_t)wid * 3 + s] =
          make_float4(vals[4*s] * inv, vals[4*s+1] * inv, vals[4*s+2] * inv, 0.f);
    }
    tau3[wid] = t3;
    if (COMPACT) nbr[(size_t)wid * KMAX + 0] = (u16)i;   // self, class 0
  }
}

// Kernel B (fast): one wave per point, lane L handles neighbor slot L.
__global__ __launch_bounds__(256) void kernelB_fast(
    const float4* __restrict__ xci, const float* __restrict__ wlin,
    const float* __restrict__ blin, const u16* __restrict__ nbr,
    float* __restrict__ out) {
  const int wid  = (blockIdx.x * 256 + threadIdx.x) >> 6;  // global point id
  const int lane = threadIdx.x & 63;
  const int pbase = wid & ~(MPTS - 1);                     // batch start

  const u16 e = nbr[(size_t)wid * KMAX + lane];
  const int cl = e >> 11;
  const int gj = pbase + (e & (MPTS - 1));

  const float4 ci0 = xci[(size_t)wid*3 + 0];
  const float4 ci1 = xci[(size_t)wid*3 + 1];
  const float4 ci2 = xci[(size_t)wid*3 + 2];

  float s0 = 0.f, s1 = 0.f, s2 = 0.f, n0 = 0.f, n1 = 0.f, n2 = 0.f;
  if (cl <= 2) {
    const float4 cj2 = xci[(size_t)gj*3 + 2];
    float ux = ci2.x - cj2.x, uy = ci2.y - cj2.y, uz = ci2.z - cj2.z;
    s2 = sqrtf(fmaxf(ux*ux + uy*uy + uz*uz, 1e-12f)); n2 = 1.f;
    if (cl <= 1) {
      const float4 cj1 = xci[(size_t)gj*3 + 1];
      ux = ci1.x - cj1.x; uy = ci1.y - cj1.y; uz = ci1.z - cj1.z;
      s1 = sqrtf(fmaxf(ux*ux + uy*uy + uz*uz, 1e-12f)); n1 = 1.f;
      if (cl == 0) {
        const float4 cj0 = xci[(size_t)gj*3 + 0];
        ux = ci0.x - cj0.x; uy = ci0.y - cj0.y; uz = ci0.z - cj0.z;
        s0 = sqrtf(fmaxf(ux*ux + uy*uy + uz*uz, 1e-12f)); n0 = 1.f;
      }
    }
  }

  float vals[6] = {s0, s1, s2, n0, n1, n2};
#pragma unroll
  for (int v = 0; v < 6; ++v)
#pragma unroll
    for (int off = 32; off > 0; off >>= 1)
      vals[v] += __shfl_xor(vals[v], off, 64);

  if (lane == 0) {
    const float msg0 = vals[0] / vals[3];
    const float msg1 = vals[1] / vals[4];
    const float msg2 = vals[2] / vals[5];
    const float z = wlin[0]*msg0 + wlin[1]*msg1 + wlin[2]*msg2 + blin[0];
    out[wid] = 1.f / (1.f + expf(-z));
  }
}

// Kernel B (fallback, ws too small): full scan with tau3 thresholds.
__global__ __launch_bounds__(256) void kernelB_slow(
    const float* __restrict__ pos, const float* __restrict__ wlin,
    const float* __restrict__ blin, const float4* __restrict__ xci,
    const float* __restrict__ tau3, float* __restrict__ out) {
  const int wid  = (blockIdx.x * 256 + threadIdx.x) >> 6;
  const int lane = threadIdx.x & 63;
  const int b = wid >> 11;
  const int i = wid & (MPTS - 1);
  const float* posb = pos + b * MPTS * 3;
  const int pbase = b * MPTS;

  const float pix = posb[3*i+0], piy = posb[3*i+1], piz = posb[3*i+2];
  const float t3 = tau3[wid];
  const float thr0 = fminf(0.01f, t3);
  const float thr1 = fminf(0.04f, t3);

  const float4 ci0 = xci[(size_t)wid*3 + 0];
  const float4 ci1 = xci[(size_t)wid*3 + 1];
  const float4 ci2 = xci[(size_t)wid*3 + 2];

  float s0=0.f, s1=0.f, s2=0.f, n0=0.f, n1=0.f, n2=0.f;
  for (int k = 0; k < NT; ++k) {
    const int j = k * 64 + lane;
    const float dx = posb[3*j+0] - pix;
    const float dy = posb[3*j+1] - piy;
    const float dz = posb[3*j+2] - piz;
    const float a3 = dx*dx + dy*dy + dz*dz;
    if (a3 <= t3) {
      const float4 cj2 = xci[(size_t)(pbase + j)*3 + 2];
      float ux = ci2.x-cj2.x, uy = ci2.y-cj2.y, uz = ci2.z-cj2.z;
      s2 += sqrtf(fmaxf(ux*ux+uy*uy+uz*uz, 1e-12f)); n2 += 1.f;
      if (a3 <= thr1) {
        const float4 cj1 = xci[(size_t)(pbase + j)*3 + 1];
        ux = ci1.x-cj1.x; uy = ci1.y-cj1.y; uz = ci1.z-cj1.z;
        s1 += sqrtf(fmaxf(ux*ux+uy*uy+uz*uz, 1e-12f)); n1 += 1.f;
        if (a3 <= thr0) {
          const float4 cj0 = xci[(size_t)(pbase + j)*3 + 0];
          ux = ci0.x-cj0.x; uy = ci0.y-cj0.y; uz = ci0.z-cj0.z;
          s0 += sqrtf(fmaxf(ux*ux+uy*uy+uz*uz, 1e-12f)); n0 += 1.f;
        }
      }
    }
  }

  float vals[6] = {s0, s1, s2, n0, n1, n2};
#pragma unroll
  for (int v = 0; v < 6; ++v)
#pragma unroll
    for (int off = 32; off > 0; off >>= 1)
      vals[v] += __shfl_xor(vals[v], off, 64);

  if (lane == 0) {
    const float msg0 = vals[0] / vals[3];
    const float msg1 = vals[1] / vals[4];
    const float msg2 = vals[2] / vals[5];
    const float z = wlin[0]*msg0 + wlin[1]*msg1 + wlin[2]*msg2 + blin[0];
    out[wid] = 1.f / (1.f + expf(-z));
  }
}

extern "C" void kernel_launch(void* const* d_in, const int* in_sizes, int n_in,
                              void* d_out, int out_size, void* d_ws, size_t ws_size,
                              hipStream_t stream) {
  (void)in_sizes; (void)n_in; (void)out_size;
  const float* x    = (const float*)d_in[0];   // [8,2048,3]
  const float* pos  = (const float*)d_in[1];   // [8,2048,3]
  const float* wlin = (const float*)d_in[2];   // [1,3]
  const float* blin = (const float*)d_in[3];   // [1]
  float* out = (float*)d_out;

  const size_t npts = (size_t)NBATCH * MPTS;
  const size_t xci_bytes = npts * 3 * sizeof(float4);   // 786,432
  const size_t tau_bytes = npts * sizeof(float);        //  65,536
  const size_t nbr_bytes = npts * KMAX * sizeof(u16);   // 2,097,152
  float4* xci = (float4*)d_ws;
  float* tau3 = (float*)((char*)d_ws + xci_bytes);
  u16* nbr    = (u16*)((char*)d_ws + xci_bytes + tau_bytes);
  const bool fast = ws_size >= xci_bytes + tau_bytes + nbr_bytes;

  const int nblocks = (int)(npts * 64 / 256);   // 4 waves (points) per block
  if (fast) {
    kernelA<true><<<nblocks, 256, 0, stream>>>(x, pos, xci, tau3, nbr);
    kernelB_fast<<<nblocks, 256, 0, stream>>>(xci, wlin, blin, nbr, out);
  } else {
    kernelA<false><<<nblocks, 256, 0, stream>>>(x, pos, xci, tau3, nbr);
    kernelB_slow<<<nblocks, 256, 0, stream>>>(pos, wlin, blin, xci, tau3, out);
  }
}

// Round 6
// 155.478 us; speedup vs baseline: 2.4525x; 1.2665x over previous
//
#include <hip/hip_runtime.h>
#include <math.h>

#define MPTS 2048
#define NBATCH 8
#define NT 32            // MPTS / 64 candidates per lane
#define KMAX 64
#define NBIN 256

typedef unsigned short u16;
typedef unsigned int u32;
typedef unsigned long long u64;

// Exact 64th-smallest threshold from a per-wave LDS histogram.
// h: this wave's 256-bin histogram (already built over values <= R, bin=min(255,d*SC)).
// bv/cnt: per-wave scratch for bin-B values. d: per-lane register array (NT vals).
// Returns t with |{d <= t}| == 64 exactly, or R if count(R) <= 64.
static __device__ __forceinline__ float kth_from_hist(
    u32* h, float* bv, u32* cnt, const float* d,
    float SC, float R, int lane) {
  // --- scan: lane owns bins 4*lane .. 4*lane+3
  const uint4 hv = *reinterpret_cast<const uint4*>(&h[lane * 4]);
  const u32 s4 = hv.x + hv.y + hv.z + hv.w;
  u32 incl = s4;
#pragma unroll
  for (int off = 1; off < 64; off <<= 1) {
    const u32 t = __shfl_up(incl, off, 64);
    if (lane >= off) incl += t;
  }
  const u32 total = __shfl(incl, 63, 64);
  if (total <= 64u) return R;                 // no truncation
  const u32 excl = incl - s4;
  const u64 msk = __ballot((excl < 64u) && (incl >= 64u));
  const int L = __builtin_ctzll(msk);
  const u32 c0 = __shfl(excl, L, 64);
  const u32 g0 = __shfl(hv.x, L, 64);
  const u32 g1 = __shfl(hv.y, L, 64);
  const u32 g2 = __shfl(hv.z, L, 64);
  const u32 g3 = __shfl(hv.w, L, 64);
  const u32 c1 = c0 + g0, c2v = c1 + g1, c3v = c2v + g2;
  int B; u32 cb, n;
  if (c1 >= 64u)       { B = 4*L + 0; cb = c0;  n = g0; }
  else if (c2v >= 64u) { B = 4*L + 1; cb = c1;  n = g1; }
  else if (c3v >= 64u) { B = 4*L + 2; cb = c2v; n = g2; }
  else                 { B = 4*L + 3; cb = c3v; n = g3; }

  // --- compact bin-B values into LDS (per-wave private; DS ops in-order per wave)
#pragma unroll
  for (int k = 0; k < NT; ++k) {
    int bk = (int)(d[k] * SC); bk = bk > 255 ? 255 : bk;
    if ((d[k] <= R) && (bk == B)) {
      const u32 slot = atomicAdd(cnt, 1u);
      if (slot < (u32)KMAX) bv[slot] = d[k];
    }
  }

  if (n <= (u32)KMAX) {
    // --- stable rank-select the (64-cb)-th smallest (0-indexed 63-cb)
    const int nn = (int)n;
    const float v = (lane < nn) ? bv[lane] : 3.0e38f;
    u32 rank = 0;
    for (int cc = 0; cc < nn; ++cc) {
      const float w = __shfl(v, cc, 64);
      rank += ((w < v) || (w == v && cc < lane)) ? 1u : 0u;
    }
    const int m0 = 63 - (int)cb;
    const u64 sm = __ballot((lane < nn) && (rank == (u32)m0));
    const int SL = __builtin_ctzll(sm);
    return __shfl(v, SL, 64);
  }

  // --- fallback (bin overflow; ~never): bisect within bin B
  float lo = (float)B * (R * (1.0f / 256.0f));
  float hi = (float)(B + 1) * (R * (1.0f / 256.0f));
  for (int it = 0; it < 26; ++it) {
    const float mid = 0.5f * (lo + hi);
    int c = 0;
#pragma unroll
    for (int k = 0; k < NT; ++k) c += __popcll(__ballot(d[k] <= mid));
    if (c >= 64) { hi = mid; if (c == 64) break; }
    else lo = mid;
  }
  return hi;
}

// Kernel A: per point -> x_centers (3 scales, interleaved float4) + tau3 +
// compacted 3D neighbor list: 64 x u16 {idx[10:0] | class[12:11]},
// slot 0 = self, class 3 = invalid.
template <bool COMPACT>
__global__ __launch_bounds__(256) void kernelA(
    const float* __restrict__ x, const float* __restrict__ pos,
    float4* __restrict__ xci, float* __restrict__ tau3, u16* __restrict__ nbr) {
  __shared__ __align__(16) u32 hist[4][2 * NBIN];
  __shared__ float bvals[4][2][KMAX];
  __shared__ u32 bcnt[4][2];

  const int wv   = threadIdx.x >> 6;
  const int lane = threadIdx.x & 63;
  const int wid  = (blockIdx.x * 256 + threadIdx.x) >> 6;   // global point id
  const int b = wid >> 11;
  const int i = wid & (MPTS - 1);
  const float* posb = pos + b * MPTS * 3;
  const float* xb   = x   + b * MPTS * 3;

  const float pix = posb[3*i+0], piy = posb[3*i+1], piz = posb[3*i+2];
  const float xix = xb[3*i+0],   xiy = xb[3*i+1],   xiz = xb[3*i+2];

  const float R3sq = 0.16f, R6sq = 0.2025f;
  const float SC3 = 256.0f / 0.16f, SC6 = 256.0f / 0.2025f;

  // zero per-wave LDS (in-order DS: visible before the atomics below)
  u32* hw = hist[wv];
#pragma unroll
  for (int z = 0; z < 2 * NBIN / 64; ++z) hw[z * 64 + lane] = 0;
  if (lane < 2) bcnt[wv][lane] = 0;

  float d3a[NT], d6a[NT];
#pragma unroll
  for (int k = 0; k < NT; ++k) {
    const int j = k * 64 + lane;
    const float dx = posb[3*j+0] - pix;
    const float dy = posb[3*j+1] - piy;
    const float dz = posb[3*j+2] - piz;
    const float a3 = dx*dx + dy*dy + dz*dz;
    const float ex = xb[3*j+0] - xix;
    const float ey = xb[3*j+1] - xiy;
    const float ez = xb[3*j+2] - xiz;
    d3a[k] = a3;
    d6a[k] = a3 + ex*ex + ey*ey + ez*ez;
    if (a3 <= R3sq) {
      int b3 = (int)(a3 * SC3); b3 = b3 > 255 ? 255 : b3;
      atomicAdd(&hw[b3], 1u);
    }
    const float a6 = d6a[k];
    if (a6 <= R6sq) {
      int b6 = (int)(a6 * SC6); b6 = b6 > 255 ? 255 : b6;
      atomicAdd(&hw[NBIN + b6], 1u);
    }
  }

  const float t3 = kth_from_hist(hw,        bvals[wv][0], &bcnt[wv][0], d3a, SC3, R3sq, lane);
  const float t6 = kth_from_hist(hw + NBIN, bvals[wv][1], &bcnt[wv][1], d6a, SC6, R6sq, lane);

  const float thr0 = fminf(0.0225f, t6);
  const float thr1 = fminf(0.0625f, t6);

  float vals[12];  // {sx,sy,sz,n} x 3 scales
#pragma unroll
  for (int v = 0; v < 12; ++v) vals[v] = 0.f;

  int base = 1;    // slot 0 reserved for self
#pragma unroll
  for (int k = 0; k < NT; ++k) {
    const int j = k * 64 + lane;
    if (d6a[k] <= t6) {
      const float xjx = xb[3*j+0], xjy = xb[3*j+1], xjz = xb[3*j+2];
      vals[8] += xjx; vals[9] += xjy; vals[10] += xjz; vals[11] += 1.f;
      if (d6a[k] <= thr1) {
        vals[4] += xjx; vals[5] += xjy; vals[6] += xjz; vals[7] += 1.f;
        if (d6a[k] <= thr0) {
          vals[0] += xjx; vals[1] += xjy; vals[2] += xjz; vals[3] += 1.f;
        }
      }
    }
    if (COMPACT) {
      const bool sel = (d3a[k] <= t3) && (j != i);
      const u64 mask = __ballot(sel);
      const int rank = __builtin_amdgcn_mbcnt_hi(
          (unsigned)(mask >> 32), __builtin_amdgcn_mbcnt_lo((unsigned)mask, 0));
      const int slot = base + rank;
      if (sel && slot < KMAX) {
        const int cl = (d3a[k] > 0.01f) + (d3a[k] > 0.04f);
        nbr[(size_t)wid * KMAX + slot] = (u16)(j | (cl << 11));
      }
      base += __popcll(mask);
    }
  }

#pragma unroll
  for (int v = 0; v < 12; ++v)
#pragma unroll
    for (int off = 32; off > 0; off >>= 1)
      vals[v] += __shfl_xor(vals[v], off, 64);

  if (COMPACT) {
    const int total = (base < KMAX) ? base : KMAX;
    if (lane >= total) nbr[(size_t)wid * KMAX + lane] = (u16)(3u << 11);
  }

  if (lane == 0) {
#pragma unroll
    for (int s = 0; s < 3; ++s) {
      const float inv = 1.f / vals[4*s + 3];
      xci[(size_t)wid * 3 + s] =
          make_float4(vals[4*s] * inv, vals[4*s+1] * inv, vals[4*s+2] * inv, 0.f);
    }
    tau3[wid] = t3;
    if (COMPACT) nbr[(size_t)wid * KMAX + 0] = (u16)i;   // self, class 0
  }
}

// Kernel B (fast): one wave per point, lane L handles neighbor slot L.
__global__ __launch_bounds__(256) void kernelB_fast(
    const float4* __restrict__ xci, const float* __restrict__ wlin,
    const float* __restrict__ blin, const u16* __restrict__ nbr,
    float* __restrict__ out) {
  const int wid  = (blockIdx.x * 256 + threadIdx.x) >> 6;  // global point id
  const int lane = threadIdx.x & 63;
  const int pbase = wid & ~(MPTS - 1);                     // batch start

  const u16 e = nbr[(size_t)wid * KMAX + lane];
  const int cl = e >> 11;
  const int gj = pbase + (e & (MPTS - 1));

  const float4 ci0 = xci[(size_t)wid*3 + 0];
  const float4 ci1 = xci[(size_t)wid*3 + 1];
  const float4 ci2 = xci[(size_t)wid*3 + 2];

  float s0 = 0.f, s1 = 0.f, s2 = 0.f, n0 = 0.f, n1 = 0.f, n2 = 0.f;
  if (cl <= 2) {
    const float4 cj2 = xci[(size_t)gj*3 + 2];
    float ux = ci2.x - cj2.x, uy = ci2.y - cj2.y, uz = ci2.z - cj2.z;
    s2 = sqrtf(fmaxf(ux*ux + uy*uy + uz*uz, 1e-12f)); n2 = 1.f;
    if (cl <= 1) {
      const float4 cj1 = xci[(size_t)gj*3 + 1];
      ux = ci1.x - cj1.x; uy = ci1.y - cj1.y; uz = ci1.z - cj1.z;
      s1 = sqrtf(fmaxf(ux*ux + uy*uy + uz*uz, 1e-12f)); n1 = 1.f;
      if (cl == 0) {
        const float4 cj0 = xci[(size_t)gj*3 + 0];
        ux = ci0.x - cj0.x; uy = ci0.y - cj0.y; uz = ci0.z - cj0.z;
        s0 = sqrtf(fmaxf(ux*ux + uy*uy + uz*uz, 1e-12f)); n0 = 1.f;
      }
    }
  }

  float vals[6] = {s0, s1, s2, n0, n1, n2};
#pragma unroll
  for (int v = 0; v < 6; ++v)
#pragma unroll
    for (int off = 32; off > 0; off >>= 1)
      vals[v] += __shfl_xor(vals[v], off, 64);

  if (lane == 0) {
    const float msg0 = vals[0] / vals[3];
    const float msg1 = vals[1] / vals[4];
    const float msg2 = vals[2] / vals[5];
    const float z = wlin[0]*msg0 + wlin[1]*msg1 + wlin[2]*msg2 + blin[0];
    out[wid] = 1.f / (1.f + expf(-z));
  }
}

// Kernel B (fallback, ws too small): full scan with tau3 thresholds.
__global__ __launch_bounds__(256) void kernelB_slow(
    const float* __restrict__ pos, const float* __restrict__ wlin,
    const float* __restrict__ blin, const float4* __restrict__ xci,
    const float* __restrict__ tau3, float* __restrict__ out) {
  const int wid  = (blockIdx.x * 256 + threadIdx.x) >> 6;
  const int lane = threadIdx.x & 63;
  const int b = wid >> 11;
  const int i = wid & (MPTS - 1);
  const float* posb = pos + b * MPTS * 3;
  const int pbase = b * MPTS;

  const float pix = posb[3*i+0], piy = posb[3*i+1], piz = posb[3*i+2];
  const float t3 = tau3[wid];
  const float thr0 = fminf(0.01f, t3);
  const float thr1 = fminf(0.04f, t3);

  const float4 ci0 = xci[(size_t)wid*3 + 0];
  const float4 ci1 = xci[(size_t)wid*3 + 1];
  const float4 ci2 = xci[(size_t)wid*3 + 2];

  float s0=0.f, s1=0.f, s2=0.f, n0=0.f, n1=0.f, n2=0.f;
  for (int k = 0; k < NT; ++k) {
    const int j = k * 64 + lane;
    const float dx = posb[3*j+0] - pix;
    const float dy = posb[3*j+1] - piy;
    const float dz = posb[3*j+2] - piz;
    const float a3 = dx*dx + dy*dy + dz*dz;
    if (a3 <= t3) {
      const float4 cj2 = xci[(size_t)(pbase + j)*3 + 2];
      float ux = ci2.x-cj2.x, uy = ci2.y-cj2.y, uz = ci2.z-cj2.z;
      s2 += sqrtf(fmaxf(ux*ux+uy*uy+uz*uz, 1e-12f)); n2 += 1.f;
      if (a3 <= thr1) {
        const float4 cj1 = xci[(size_t)(pbase + j)*3 + 1];
        ux = ci1.x-cj1.x; uy = ci1.y-cj1.y; uz = ci1.z-cj1.z;
        s1 += sqrtf(fmaxf(ux*ux+uy*uy+uz*uz, 1e-12f)); n1 += 1.f;
        if (a3 <= thr0) {
          const float4 cj0 = xci[(size_t)(pbase + j)*3 + 0];
          ux = ci0.x-cj0.x; uy = ci0.y-cj0.y; uz = ci0.z-cj0.z;
          s0 += sqrtf(fmaxf(ux*ux+uy*uy+uz*uz, 1e-12f)); n0 += 1.f;
        }
      }
    }
  }

  float vals[6] = {s0, s1, s2, n0, n1, n2};
#pragma unroll
  for (int v = 0; v < 6; ++v)
#pragma unroll
    for (int off = 32; off > 0; off >>= 1)
      vals[v] += __shfl_xor(vals[v], off, 64);

  if (lane == 0) {
    const float msg0 = vals[0] / vals[3];
    const float msg1 = vals[1] / vals[4];
    const float msg2 = vals[2] / vals[5];
    const float z = wlin[0]*msg0 + wlin[1]*msg1 + wlin[2]*msg2 + blin[0];
    out[wid] = 1.f / (1.f + expf(-z));
  }
}

extern "C" void kernel_launch(void* const* d_in, const int* in_sizes, int n_in,
                              void* d_out, int out_size, void* d_ws, size_t ws_size,
                              hipStream_t stream) {
  (void)in_sizes; (void)n_in; (void)out_size;
  const float* x    = (const float*)d_in[0];   // [8,2048,3]
  const float* pos  = (const float*)d_in[1];   // [8,2048,3]
  const float* wlin = (const float*)d_in[2];   // [1,3]
  const float* blin = (const float*)d_in[3];   // [1]
  float* out = (float*)d_out;

  const size_t npts = (size_t)NBATCH * MPTS;
  const size_t xci_bytes = npts * 3 * sizeof(float4);   // 786,432
  const size_t tau_bytes = npts * sizeof(float);        //  65,536
  const size_t nbr_bytes = npts * KMAX * sizeof(u16);   // 2,097,152
  float4* xci = (float4*)d_ws;
  float* tau3 = (float*)((char*)d_ws + xci_bytes);
  u16* nbr    = (u16*)((char*)d_ws + xci_bytes + tau_bytes);
  const bool fast = ws_size >= xci_bytes + tau_bytes + nbr_bytes;

  const int nblocks = (int)(npts * 64 / 256);   // 4 waves (points) per block
  if (fast) {
    kernelA<true><<<nblocks, 256, 0, stream>>>(x, pos, xci, tau3, nbr);
    kernelB_fast<<<nblocks, 256, 0, stream>>>(xci, wlin, blin, nbr, out);
  } else {
    kernelA<false><<<nblocks, 256, 0, stream>>>(x, pos, xci, tau3, nbr);
    kernelB_slow<<<nblocks, 256, 0, stream>>>(pos, wlin, blin, xci, tau3, out);
  }
}

// Round 7
// 117.977 us; speedup vs baseline: 3.2321x; 1.3179x over previous
//
#include <hip/hip_runtime.h>
#include <math.h>

#define MPTS 2048
#define NBATCH 8
#define NT 32            // MPTS / 64 candidates per lane
#define KMAX 64
#define NBIN 256
#define BCAP 16          // max captured values in the rank bin (overflow -> bisect)
#define TPB 512          // kernelA threads/block = 8 waves = 8 points

typedef unsigned short u16;
typedef unsigned int u32;
typedef unsigned long long u64;

// Kernel A: per point -> x_centers (3 scales, interleaved float4) + tau3 +
// compacted 3D neighbor list: 64 x u16 {idx[10:0] | class[12:11]},
// slot 0 = self, class 3 = invalid.
// 8 waves/block, one point per wave, whole batch staged in LDS.
template <bool COMPACT>
__global__ __launch_bounds__(TPB, 4) void kernelA(
    const float* __restrict__ x, const float* __restrict__ pos,
    float4* __restrict__ xci, float* __restrict__ tau3, u16* __restrict__ nbr) {
  __shared__ __align__(16) float4 P4[MPTS];          // 32 KB (pos.xyz, x.x)
  __shared__ __align__(16) float2 X2[MPTS];          // 16 KB (x.y, x.z)
  __shared__ __align__(16) u32 histAll[8 * 2 * NBIN];// 16 KB
  __shared__ float bv[8][2][BCAP];                   //  4 KB
  __shared__ u32 bcnt[8][2];

  const int tid  = threadIdx.x;
  const int wv   = tid >> 6;
  const int lane = tid & 63;
  const int wid  = blockIdx.x * (TPB / 64) + wv;     // global point id
  const int b    = wid >> 11;                        // block-uniform (256 blk/batch)
  const int i    = wid & (MPTS - 1);
  const float* posb = pos + b * MPTS * 3;
  const float* xb   = x   + b * MPTS * 3;

  // cooperative stage of the whole batch
  for (int p = tid; p < MPTS; p += TPB) {
    P4[p] = make_float4(posb[3*p+0], posb[3*p+1], posb[3*p+2], xb[3*p+0]);
    X2[p] = make_float2(xb[3*p+1], xb[3*p+2]);
  }
#pragma unroll
  for (int z = 0; z < 8 * 2 * NBIN / TPB; ++z) histAll[z * TPB + tid] = 0;
  if (tid < 16) ((u32*)bcnt)[tid] = 0;
  __syncthreads();

  u32* hw = &histAll[wv * 2 * NBIN];                 // per-wave private histogram

  const float4 pi4 = P4[i];
  const float2 xi2 = X2[i];
  const float pix = pi4.x, piy = pi4.y, piz = pi4.z;
  const float xix = pi4.w, xiy = xi2.x, xiz = xi2.y;

  const float R3sq = 0.16f, R6sq = 0.2025f;
  const float SC3 = 256.0f / 0.16f, SC6 = 256.0f / 0.2025f;

  // --- pass 1: distances (registers) + per-wave histograms
  float d3a[NT], d6a[NT];
#pragma unroll
  for (int k = 0; k < NT; ++k) {
    const int j = k * 64 + lane;
    const float4 pj = P4[j];
    const float2 xj = X2[j];
    const float dx = pj.x - pix, dy = pj.y - piy, dz = pj.z - piz;
    const float a3 = dx*dx + dy*dy + dz*dz;
    const float ex = pj.w - xix, ey = xj.x - xiy, ez = xj.y - xiz;
    const float a6 = a3 + ex*ex + ey*ey + ez*ez;
    d3a[k] = a3; d6a[k] = a6;
    if (a3 <= R3sq) { int bb = (int)(a3 * SC3); bb = bb > 255 ? 255 : bb; atomicAdd(&hw[bb], 1u); }
    if (a6 <= R6sq) { int bb = (int)(a6 * SC6); bb = bb > 255 ? 255 : bb; atomicAdd(&hw[NBIN + bb], 1u); }
  }

  // --- fused dual scan (wave-private hist; DS ops in-order per wave)
  const uint4 h3 = *reinterpret_cast<const uint4*>(&hw[lane * 4]);
  const uint4 h6 = *reinterpret_cast<const uint4*>(&hw[NBIN + lane * 4]);
  const u32 s3 = h3.x + h3.y + h3.z + h3.w;
  const u32 s6 = h6.x + h6.y + h6.z + h6.w;
  u32 in3 = s3, in6 = s6;
#pragma unroll
  for (int off = 1; off < 64; off <<= 1) {
    const u32 a = __shfl_up(in3, off, 64);
    const u32 c = __shfl_up(in6, off, 64);
    if (lane >= off) { in3 += a; in6 += c; }
  }
  const u32 tot3 = __shfl(in3, 63, 64), tot6 = __shfl(in6, 63, 64);
  bool done3 = (tot3 <= 64u), done6 = (tot6 <= 64u);
  float t3 = R3sq, t6 = R6sq;

  int B3 = 0, B6 = 0; u32 cb3 = 0, cb6 = 0, n3 = 0, n6 = 0;
  if (!done3) {
    const u32 ex = in3 - s3;
    const u64 m = __ballot((ex < 64u) && (in3 >= 64u));
    const int L = __builtin_ctzll(m);
    const u32 c0 = __shfl(ex, L, 64);
    const u32 g0 = __shfl(h3.x, L, 64), g1 = __shfl(h3.y, L, 64);
    const u32 g2 = __shfl(h3.z, L, 64), g3 = __shfl(h3.w, L, 64);
    const u32 c1 = c0 + g0, c2 = c1 + g1, c3 = c2 + g2;
    if (c1 >= 64u)      { B3 = 4*L;   cb3 = c0; n3 = g0; }
    else if (c2 >= 64u) { B3 = 4*L+1; cb3 = c1; n3 = g1; }
    else if (c3 >= 64u) { B3 = 4*L+2; cb3 = c2; n3 = g2; }
    else                { B3 = 4*L+3; cb3 = c3; n3 = g3; }
  }
  if (!done6) {
    const u32 ex = in6 - s6;
    const u64 m = __ballot((ex < 64u) && (in6 >= 64u));
    const int L = __builtin_ctzll(m);
    const u32 c0 = __shfl(ex, L, 64);
    const u32 g0 = __shfl(h6.x, L, 64), g1 = __shfl(h6.y, L, 64);
    const u32 g2 = __shfl(h6.z, L, 64), g3 = __shfl(h6.w, L, 64);
    const u32 c1 = c0 + g0, c2 = c1 + g1, c3 = c2 + g2;
    if (c1 >= 64u)      { B6 = 4*L;   cb6 = c0; n6 = g0; }
    else if (c2 >= 64u) { B6 = 4*L+1; cb6 = c1; n6 = g1; }
    else if (c3 >= 64u) { B6 = 4*L+2; cb6 = c2; n6 = g2; }
    else                { B6 = 4*L+3; cb6 = c3; n6 = g3; }
  }

  if (!done3 || !done6) {
    // --- fused compaction of the two rank bins
#pragma unroll
    for (int k = 0; k < NT; ++k) {
      if (!done3) {
        int bb = (int)(d3a[k] * SC3); bb = bb > 255 ? 255 : bb;
        if ((d3a[k] <= R3sq) && (bb == B3)) {
          const u32 s = atomicAdd(&bcnt[wv][0], 1u);
          if (s < (u32)BCAP) bv[wv][0][s] = d3a[k];
        }
      }
      if (!done6) {
        int bb = (int)(d6a[k] * SC6); bb = bb > 255 ? 255 : bb;
        if ((d6a[k] <= R6sq) && (bb == B6)) {
          const u32 s = atomicAdd(&bcnt[wv][1], 1u);
          if (s < (u32)BCAP) bv[wv][1][s] = d6a[k];
        }
      }
    }
    // --- fused dual stable rank-select
    const bool rs3 = !done3 && (n3 <= (u32)BCAP);
    const bool rs6 = !done6 && (n6 <= (u32)BCAP);
    const int nn3 = rs3 ? (int)n3 : 0, nn6 = rs6 ? (int)n6 : 0;
    const float v3 = (lane < nn3) ? bv[wv][0][lane] : 3.0e38f;
    const float v6 = (lane < nn6) ? bv[wv][1][lane] : 3.0e38f;
    u32 r3 = 0, r6 = 0;
    const int nmax = nn3 > nn6 ? nn3 : nn6;
    for (int cc = 0; cc < nmax; ++cc) {
      const float w3 = __shfl(v3, cc, 64);
      const float w6 = __shfl(v6, cc, 64);
      r3 += ((w3 < v3) || (w3 == v3 && cc < lane)) ? 1u : 0u;
      r6 += ((w6 < v6) || (w6 == v6 && cc < lane)) ? 1u : 0u;
    }
    if (rs3) {
      const u64 sm = __ballot((lane < nn3) && (r3 == (u32)(63 - (int)cb3)));
      t3 = __shfl(v3, __builtin_ctzll(sm), 64);
      done3 = true;
    }
    if (rs6) {
      const u64 sm = __ballot((lane < nn6) && (r6 == (u32)(63 - (int)cb6)));
      t6 = __shfl(v6, __builtin_ctzll(sm), 64);
      done6 = true;
    }
    // --- bisect fallback (bin overflow; ~never)
    if (!done3) {
      float lo = (float)B3 * (R3sq / 256.0f), hi = lo + R3sq / 256.0f;
      for (int it = 0; it < 26; ++it) {
        const float mid = 0.5f * (lo + hi);
        int c = 0;
#pragma unroll
        for (int k = 0; k < NT; ++k) c += __popcll(__ballot(d3a[k] <= mid));
        if (c >= 64) { hi = mid; if (c == 64) break; } else lo = mid;
      }
      t3 = hi;
    }
    if (!done6) {
      float lo = (float)B6 * (R6sq / 256.0f), hi = lo + R6sq / 256.0f;
      for (int it = 0; it < 26; ++it) {
        const float mid = 0.5f * (lo + hi);
        int c = 0;
#pragma unroll
        for (int k = 0; k < NT; ++k) c += __popcll(__ballot(d6a[k] <= mid));
        if (c >= 64) { hi = mid; if (c == 64) break; } else lo = mid;
      }
      t6 = hi;
    }
  }

  // --- pass 2: masked means over 6D top-64 + 3D neighbor compaction
  const float thr0 = fminf(0.0225f, t6);
  const float thr1 = fminf(0.0625f, t6);

  float vals[12];  // {sx,sy,sz,n} x 3 scales
#pragma unroll
  for (int v = 0; v < 12; ++v) vals[v] = 0.f;

  int base = 1;    // slot 0 reserved for self
#pragma unroll
  for (int k = 0; k < NT; ++k) {
    const int j = k * 64 + lane;
    if (d6a[k] <= t6) {
      const float xjx = P4[j].w;
      const float2 xj = X2[j];
      vals[8] += xjx; vals[9] += xj.x; vals[10] += xj.y; vals[11] += 1.f;
      if (d6a[k] <= thr1) {
        vals[4] += xjx; vals[5] += xj.x; vals[6] += xj.y; vals[7] += 1.f;
        if (d6a[k] <= thr0) {
          vals[0] += xjx; vals[1] += xj.x; vals[2] += xj.y; vals[3] += 1.f;
        }
      }
    }
    if (COMPACT) {
      const bool sel = (d3a[k] <= t3) && (j != i);
      const u64 mask = __ballot(sel);
      const int rank = __builtin_amdgcn_mbcnt_hi(
          (unsigned)(mask >> 32), __builtin_amdgcn_mbcnt_lo((unsigned)mask, 0));
      const int slot = base + rank;
      if (sel && slot < KMAX) {
        const int cl = (d3a[k] > 0.01f) + (d3a[k] > 0.04f);
        nbr[(size_t)wid * KMAX + slot] = (u16)(j | (cl << 11));
      }
      base += __popcll(mask);
    }
  }

#pragma unroll
  for (int v = 0; v < 12; ++v)
#pragma unroll
    for (int off = 32; off > 0; off >>= 1)
      vals[v] += __shfl_xor(vals[v], off, 64);

  if (COMPACT) {
    const int total = (base < KMAX) ? base : KMAX;
    if (lane >= total) nbr[(size_t)wid * KMAX + lane] = (u16)(3u << 11);
  }

  if (lane == 0) {
#pragma unroll
    for (int s = 0; s < 3; ++s) {
      const float inv = 1.f / vals[4*s + 3];
      xci[(size_t)wid * 3 + s] =
          make_float4(vals[4*s] * inv, vals[4*s+1] * inv, vals[4*s+2] * inv, 0.f);
    }
    tau3[wid] = t3;
    if (COMPACT) nbr[(size_t)wid * KMAX + 0] = (u16)i;   // self, class 0
  }
}

// Kernel B (fast): one wave per point, lane L handles neighbor slot L.
__global__ __launch_bounds__(256) void kernelB_fast(
    const float4* __restrict__ xci, const float* __restrict__ wlin,
    const float* __restrict__ blin, const u16* __restrict__ nbr,
    float* __restrict__ out) {
  const int wid  = (blockIdx.x * 256 + threadIdx.x) >> 6;  // global point id
  const int lane = threadIdx.x & 63;
  const int pbase = wid & ~(MPTS - 1);                     // batch start

  const u16 e = nbr[(size_t)wid * KMAX + lane];
  const int cl = e >> 11;
  const int gj = pbase + (e & (MPTS - 1));

  const float4 ci0 = xci[(size_t)wid*3 + 0];
  const float4 ci1 = xci[(size_t)wid*3 + 1];
  const float4 ci2 = xci[(size_t)wid*3 + 2];

  float s0 = 0.f, s1 = 0.f, s2 = 0.f, n0 = 0.f, n1 = 0.f, n2 = 0.f;
  if (cl <= 2) {
    const float4 cj2 = xci[(size_t)gj*3 + 2];
    float ux = ci2.x - cj2.x, uy = ci2.y - cj2.y, uz = ci2.z - cj2.z;
    s2 = sqrtf(fmaxf(ux*ux + uy*uy + uz*uz, 1e-12f)); n2 = 1.f;
    if (cl <= 1) {
      const float4 cj1 = xci[(size_t)gj*3 + 1];
      ux = ci1.x - cj1.x; uy = ci1.y - cj1.y; uz = ci1.z - cj1.z;
      s1 = sqrtf(fmaxf(ux*ux + uy*uy + uz*uz, 1e-12f)); n1 = 1.f;
      if (cl == 0) {
        const float4 cj0 = xci[(size_t)gj*3 + 0];
        ux = ci0.x - cj0.x; uy = ci0.y - cj0.y; uz = ci0.z - cj0.z;
        s0 = sqrtf(fmaxf(ux*ux + uy*uy + uz*uz, 1e-12f)); n0 = 1.f;
      }
    }
  }

  float vals[6] = {s0, s1, s2, n0, n1, n2};
#pragma unroll
  for (int v = 0; v < 6; ++v)
#pragma unroll
    for (int off = 32; off > 0; off >>= 1)
      vals[v] += __shfl_xor(vals[v], off, 64);

  if (lane == 0) {
    const float msg0 = vals[0] / vals[3];
    const float msg1 = vals[1] / vals[4];
    const float msg2 = vals[2] / vals[5];
    const float z = wlin[0]*msg0 + wlin[1]*msg1 + wlin[2]*msg2 + blin[0];
    out[wid] = 1.f / (1.f + expf(-z));
  }
}

// Kernel B (fallback, ws too small): full scan with tau3 thresholds.
__global__ __launch_bounds__(256) void kernelB_slow(
    const float* __restrict__ pos, const float* __restrict__ wlin,
    const float* __restrict__ blin, const float4* __restrict__ xci,
    const float* __restrict__ tau3, float* __restrict__ out) {
  const int wid  = (blockIdx.x * 256 + threadIdx.x) >> 6;
  const int lane = threadIdx.x & 63;
  const int b = wid >> 11;
  const int i = wid & (MPTS - 1);
  const float* posb = pos + b * MPTS * 3;
  const int pbase = b * MPTS;

  const float pix = posb[3*i+0], piy = posb[3*i+1], piz = posb[3*i+2];
  const float t3 = tau3[wid];
  const float thr0 = fminf(0.01f, t3);
  const float thr1 = fminf(0.04f, t3);

  const float4 ci0 = xci[(size_t)wid*3 + 0];
  const float4 ci1 = xci[(size_t)wid*3 + 1];
  const float4 ci2 = xci[(size_t)wid*3 + 2];

  float s0=0.f, s1=0.f, s2=0.f, n0=0.f, n1=0.f, n2=0.f;
  for (int k = 0; k < NT; ++k) {
    const int j = k * 64 + lane;
    const float dx = posb[3*j+0] - pix;
    const float dy = posb[3*j+1] - piy;
    const float dz = posb[3*j+2] - piz;
    const float a3 = dx*dx + dy*dy + dz*dz;
    if (a3 <= t3) {
      const float4 cj2 = xci[(size_t)(pbase + j)*3 + 2];
      float ux = ci2.x-cj2.x, uy = ci2.y-cj2.y, uz = ci2.z-cj2.z;
      s2 += sqrtf(fmaxf(ux*ux+uy*uy+uz*uz, 1e-12f)); n2 += 1.f;
      if (a3 <= thr1) {
        const float4 cj1 = xci[(size_t)(pbase + j)*3 + 1];
        ux = ci1.x-cj1.x; uy = ci1.y-cj1.y; uz = ci1.z-cj1.z;
        s1 += sqrtf(fmaxf(ux*ux+uy*uy+uz*uz, 1e-12f)); n1 += 1.f;
        if (a3 <= thr0) {
          const float4 cj0 = xci[(size_t)(pbase + j)*3 + 0];
          ux = ci0.x-cj0.x; uy = ci0.y-cj0.y; uz = ci0.z-cj0.z;
          s0 += sqrtf(fmaxf(ux*ux+uy*uy+uz*uz, 1e-12f)); n0 += 1.f;
        }
      }
    }
  }

  float vals[6] = {s0, s1, s2, n0, n1, n2};
#pragma unroll
  for (int v = 0; v < 6; ++v)
#pragma unroll
    for (int off = 32; off > 0; off >>= 1)
      vals[v] += __shfl_xor(vals[v], off, 64);

  if (lane == 0) {
    const float msg0 = vals[0] / vals[3];
    const float msg1 = vals[1] / vals[4];
    const float msg2 = vals[2] / vals[5];
    const float z = wlin[0]*msg0 + wlin[1]*msg1 + wlin[2]*msg2 + blin[0];
    out[wid] = 1.f / (1.f + expf(-z));
  }
}

extern "C" void kernel_launch(void* const* d_in, const int* in_sizes, int n_in,
                              void* d_out, int out_size, void* d_ws, size_t ws_size,
                              hipStream_t stream) {
  (void)in_sizes; (void)n_in; (void)out_size;
  const float* x    = (const float*)d_in[0];   // [8,2048,3]
  const float* pos  = (const float*)d_in[1];   // [8,2048,3]
  const float* wlin = (const float*)d_in[2];   // [1,3]
  const float* blin = (const float*)d_in[3];   // [1]
  float* out = (float*)d_out;

  const size_t npts = (size_t)NBATCH * MPTS;
  const size_t xci_bytes = npts * 3 * sizeof(float4);   // 786,432
  const size_t tau_bytes = npts * sizeof(float);        //  65,536
  const size_t nbr_bytes = npts * KMAX * sizeof(u16);   // 2,097,152
  float4* xci = (float4*)d_ws;
  float* tau3 = (float*)((char*)d_ws + xci_bytes);
  u16* nbr    = (u16*)((char*)d_ws + xci_bytes + tau_bytes);
  const bool fast = ws_size >= xci_bytes + tau_bytes + nbr_bytes;

  const int nblocksA = (int)(npts / (TPB / 64));   // 8 points per block
  const int nblocksB = (int)(npts * 64 / 256);
  if (fast) {
    kernelA<true><<<nblocksA, TPB, 0, stream>>>(x, pos, xci, tau3, nbr);
    kernelB_fast<<<nblocksB, 256, 0, stream>>>(xci, wlin, blin, nbr, out);
  } else {
    kernelA<false><<<nblocksA, TPB, 0, stream>>>(x, pos, xci, tau3, nbr);
    kernelB_slow<<<nblocksB, 256, 0, stream>>>(pos, wlin, blin, xci, tau3, out);
  }
}

// Round 8
// 92.746 us; speedup vs baseline: 4.1114x; 1.2720x over previous
//
#include <hip/hip_runtime.h>
#include <math.h>

#define MPTS 2048
#define NBATCH 8
#define NT 32            // MPTS / 64 candidates per lane
#define KMAX 64
#define NBIN 256
#define BCAP 8           // max captured values in the rank bin (overflow -> bisect)
#define TPB 512          // kernelA threads/block = 8 waves = 8 points

typedef unsigned short u16;
typedef unsigned int u32;
typedef unsigned long long u64;

// Kernel A: per point -> x_centers (3 scales, interleaved float4) + tau3 +
// compacted 3D neighbor list: 64 x u16 {idx[10:0] | class[12:11]}, class 3 = pad.
// 8 waves/block, one point per wave, whole batch staged in LDS.
// Exact top-64 threshold via per-wave 256-bin LDS histogram + rank-select.
template <bool COMPACT>
__global__ __launch_bounds__(TPB, 4) void kernelA(
    const float* __restrict__ x, const float* __restrict__ pos,
    float4* __restrict__ xci, float* __restrict__ tau3, u16* __restrict__ nbr) {
  __shared__ __align__(16) float4 P4[MPTS];            // 32 KB (pos.xyz, x.x)
  __shared__ __align__(16) float2 X2[MPTS];            // 16 KB (x.y, x.z)
  __shared__ __align__(16) u32 histAll[8 * 2 * NBIN];  // 16 KB
  __shared__ float bv[8][2][BCAP];                     // 512 B
  __shared__ u32 bcnt[8][2];                           // 64 B
  __shared__ u16 lst[8][2][KMAX];                      // 2 KB  [wave][metric][slot]

  const int tid  = threadIdx.x;
  const int wv   = tid >> 6;
  const int lane = tid & 63;
  const int wid  = blockIdx.x * (TPB / 64) + wv;       // global point id
  const int b    = wid >> 11;                          // block-uniform
  const int i    = wid & (MPTS - 1);
  const float* posb = pos + b * MPTS * 3;
  const float* xb   = x   + b * MPTS * 3;

  // cooperative stage of the whole batch
  for (int p = tid; p < MPTS; p += TPB) {
    P4[p] = make_float4(posb[3*p+0], posb[3*p+1], posb[3*p+2], xb[3*p+0]);
    X2[p] = make_float2(xb[3*p+1], xb[3*p+2]);
  }
  {
    uint4* h4 = reinterpret_cast<uint4*>(histAll);
#pragma unroll
    for (int z = 0; z < (8 * 2 * NBIN / 4) / TPB; ++z)
      h4[z * TPB + tid] = make_uint4(0, 0, 0, 0);
  }
  if (tid < 16) ((u32*)bcnt)[tid] = 0;
  __syncthreads();

  u32* hw = &histAll[wv * 2 * NBIN];                   // per-wave private histogram

  const float4 pi4 = P4[i];
  const float2 xi2 = X2[i];
  const float pix = pi4.x, piy = pi4.y, piz = pi4.z;
  const float xix = pi4.w, xiy = xi2.x, xiz = xi2.y;

  const float R3sq = 0.16f, R6sq = 0.2025f;
  const float SC3 = 256.0f / 0.16f, SC6 = 256.0f / 0.2025f;

  // --- pass 1: distances (registers) + per-wave histograms
  float d3a[NT], d6a[NT];
#pragma unroll
  for (int k = 0; k < NT; ++k) {
    const int j = k * 64 + lane;
    const float4 pj = P4[j];
    const float2 xj = X2[j];
    const float dx = pj.x - pix, dy = pj.y - piy, dz = pj.z - piz;
    const float a3 = dx*dx + dy*dy + dz*dz;
    const float ex = pj.w - xix, ey = xj.x - xiy, ez = xj.y - xiz;
    const float a6 = a3 + ex*ex + ey*ey + ez*ez;
    d3a[k] = a3; d6a[k] = a6;
    if (a3 <= R3sq) { int bb = (int)(a3 * SC3); bb = bb > 255 ? 255 : bb; atomicAdd(&hw[bb], 1u); }
    if (a6 <= R6sq) { int bb = (int)(a6 * SC6); bb = bb > 255 ? 255 : bb; atomicAdd(&hw[NBIN + bb], 1u); }
  }

  // --- fused dual scan (wave-private hist; DS ops in-order per wave)
  const uint4 h3 = *reinterpret_cast<const uint4*>(&hw[lane * 4]);
  const uint4 h6 = *reinterpret_cast<const uint4*>(&hw[NBIN + lane * 4]);
  const u32 s3 = h3.x + h3.y + h3.z + h3.w;
  const u32 s6 = h6.x + h6.y + h6.z + h6.w;
  u32 in3 = s3, in6 = s6;
#pragma unroll
  for (int off = 1; off < 64; off <<= 1) {
    const u32 a = __shfl_up(in3, off, 64);
    const u32 c = __shfl_up(in6, off, 64);
    if (lane >= off) { in3 += a; in6 += c; }
  }
  const u32 tot3 = __shfl(in3, 63, 64), tot6 = __shfl(in6, 63, 64);
  bool done3 = (tot3 <= 64u), done6 = (tot6 <= 64u);
  float t3 = R3sq, t6 = R6sq;

  int B3 = 0, B6 = 0; u32 cb3 = 0, cb6 = 0, n3 = 0, n6 = 0;
  if (!done3) {
    const u32 ex = in3 - s3;
    const u64 m = __ballot((ex < 64u) && (in3 >= 64u));
    const int L = __builtin_ctzll(m);
    const u32 c0 = __shfl(ex, L, 64);
    const u32 g0 = __shfl(h3.x, L, 64), g1 = __shfl(h3.y, L, 64);
    const u32 g2 = __shfl(h3.z, L, 64), g3 = __shfl(h3.w, L, 64);
    const u32 c1 = c0 + g0, c2 = c1 + g1, c3 = c2 + g2;
    if (c1 >= 64u)      { B3 = 4*L;   cb3 = c0; n3 = g0; }
    else if (c2 >= 64u) { B3 = 4*L+1; cb3 = c1; n3 = g1; }
    else if (c3 >= 64u) { B3 = 4*L+2; cb3 = c2; n3 = g2; }
    else                { B3 = 4*L+3; cb3 = c3; n3 = g3; }
  }
  if (!done6) {
    const u32 ex = in6 - s6;
    const u64 m = __ballot((ex < 64u) && (in6 >= 64u));
    const int L = __builtin_ctzll(m);
    const u32 c0 = __shfl(ex, L, 64);
    const u32 g0 = __shfl(h6.x, L, 64), g1 = __shfl(h6.y, L, 64);
    const u32 g2 = __shfl(h6.z, L, 64), g3 = __shfl(h6.w, L, 64);
    const u32 c1 = c0 + g0, c2 = c1 + g1, c3 = c2 + g2;
    if (c1 >= 64u)      { B6 = 4*L;   cb6 = c0; n6 = g0; }
    else if (c2 >= 64u) { B6 = 4*L+1; cb6 = c1; n6 = g1; }
    else if (c3 >= 64u) { B6 = 4*L+2; cb6 = c2; n6 = g2; }
    else                { B6 = 4*L+3; cb6 = c3; n6 = g3; }
  }

  if (!done3 || !done6) {
    // --- fused compaction of the two rank bins (participants ~1-4 per metric)
#pragma unroll
    for (int k = 0; k < NT; ++k) {
      if (!done3) {
        int bb = (int)(d3a[k] * SC3); bb = bb > 255 ? 255 : bb;
        if ((d3a[k] <= R3sq) && (bb == B3)) {
          const u32 s = atomicAdd(&bcnt[wv][0], 1u);
          if (s < (u32)BCAP) bv[wv][0][s] = d3a[k];
        }
      }
      if (!done6) {
        int bb = (int)(d6a[k] * SC6); bb = bb > 255 ? 255 : bb;
        if ((d6a[k] <= R6sq) && (bb == B6)) {
          const u32 s = atomicAdd(&bcnt[wv][1], 1u);
          if (s < (u32)BCAP) bv[wv][1][s] = d6a[k];
        }
      }
    }
    // --- fused dual stable rank-select (value result: tie-order independent)
    const bool rs3 = !done3 && (n3 <= (u32)BCAP);
    const bool rs6 = !done6 && (n6 <= (u32)BCAP);
    const int nn3 = rs3 ? (int)n3 : 0, nn6 = rs6 ? (int)n6 : 0;
    const float v3 = (lane < nn3) ? bv[wv][0][lane] : 3.0e38f;
    const float v6 = (lane < nn6) ? bv[wv][1][lane] : 3.0e38f;
    u32 r3 = 0, r6 = 0;
    const int nmax = nn3 > nn6 ? nn3 : nn6;
    for (int cc = 0; cc < nmax; ++cc) {
      const float w3 = __shfl(v3, cc, 64);
      const float w6 = __shfl(v6, cc, 64);
      r3 += ((w3 < v3) || (w3 == v3 && cc < lane)) ? 1u : 0u;
      r6 += ((w6 < v6) || (w6 == v6 && cc < lane)) ? 1u : 0u;
    }
    if (rs3) {
      const u64 sm = __ballot((lane < nn3) && (r3 == (u32)(63 - (int)cb3)));
      t3 = __shfl(v3, __builtin_ctzll(sm), 64);
      done3 = true;
    }
    if (rs6) {
      const u64 sm = __ballot((lane < nn6) && (r6 == (u32)(63 - (int)cb6)));
      t6 = __shfl(v6, __builtin_ctzll(sm), 64);
      done6 = true;
    }
    // --- bisect fallback (bin overflow; ~never)
    if (!done3) {
      float lo = (float)B3 * (R3sq / 256.0f), hi = lo + R3sq / 256.0f;
      for (int it = 0; it < 26; ++it) {
        const float mid = 0.5f * (lo + hi);
        int c = 0;
#pragma unroll
        for (int k = 0; k < NT; ++k) c += __popcll(__ballot(d3a[k] <= mid));
        if (c >= 64) { hi = mid; if (c == 64) break; } else lo = mid;
      }
      t3 = hi;
    }
    if (!done6) {
      float lo = (float)B6 * (R6sq / 256.0f), hi = lo + R6sq / 256.0f;
      for (int it = 0; it < 26; ++it) {
        const float mid = 0.5f * (lo + hi);
        int c = 0;
#pragma unroll
        for (int k = 0; k < NT; ++k) c += __popcll(__ballot(d6a[k] <= mid));
        if (c >= 64) { hi = mid; if (c == 64) break; } else lo = mid;
      }
      t6 = hi;
    }
  }

  // --- pass 2: ballot-compact BOTH selected sets (exactly <=64 each, self incl.)
  // entry = j | class<<11; class from FIXED ring bounds (min(r_s^2, t) folds in
  // automatically since entries already satisfy d <= t).
  int base3 = 0, base6 = 0;
#pragma unroll
  for (int k = 0; k < NT; ++k) {
    const int j = k * 64 + lane;
    const float a3 = d3a[k], a6 = d6a[k];
    const bool sel3 = (a3 <= t3);
    const bool sel6 = (a6 <= t6);
    const u64 m3 = __ballot(sel3);
    const u64 m6 = __ballot(sel6);
    const int r3 = __builtin_amdgcn_mbcnt_hi(
        (unsigned)(m3 >> 32), __builtin_amdgcn_mbcnt_lo((unsigned)m3, 0));
    const int r6 = __builtin_amdgcn_mbcnt_hi(
        (unsigned)(m6 >> 32), __builtin_amdgcn_mbcnt_lo((unsigned)m6, 0));
    if (sel3) {
      const int s = base3 + r3;
      if (s < KMAX) {
        const int cl = (a3 > 0.01f) + (a3 > 0.04f);
        lst[wv][0][s] = (u16)(j | (cl << 11));
      }
    }
    if (sel6) {
      const int s = base6 + r6;
      if (s < KMAX) {
        const int cl = (a6 > 0.0225f) + (a6 > 0.0625f);
        lst[wv][1][s] = (u16)(j | (cl << 11));
      }
    }
    base3 += __popcll(m3);
    base6 += __popcll(m6);
  }

  const int c3n = base3 < KMAX ? base3 : KMAX;
  const int c6n = base6 < KMAX ? base6 : KMAX;

  // 3D neighbor list -> global, one coalesced u16 store per lane
  if (COMPACT) {
    const u16 e3 = (lane < c3n) ? lst[wv][0][lane] : (u16)(3u << 11);
    nbr[(size_t)wid * KMAX + lane] = e3;
  }

  // 6D masked means: one 64-lane gather + ring-predicated values + reduce
  const u16 e6 = (lane < c6n) ? lst[wv][1][lane] : (u16)0xFFFF;   // cl=3 pad
  const int cl6 = (e6 >> 11) & 3;
  const int jj  = e6 & (MPTS - 1);
  const float xjx = P4[jj].w;
  const float2 xj = X2[jj];
  const bool v2 = (cl6 <= 2), v1 = (cl6 <= 1), v0 = (cl6 == 0);

  float vals[12];
  vals[0] = v0 ? xjx : 0.f; vals[1] = v0 ? xj.x : 0.f; vals[2] = v0 ? xj.y : 0.f; vals[3] = v0 ? 1.f : 0.f;
  vals[4] = v1 ? xjx : 0.f; vals[5] = v1 ? xj.x : 0.f; vals[6] = v1 ? xj.y : 0.f; vals[7] = v1 ? 1.f : 0.f;
  vals[8] = v2 ? xjx : 0.f; vals[9] = v2 ? xj.x : 0.f; vals[10] = v2 ? xj.y : 0.f; vals[11] = v2 ? 1.f : 0.f;

#pragma unroll
  for (int v = 0; v < 12; ++v)
#pragma unroll
    for (int off = 32; off > 0; off >>= 1)
      vals[v] += __shfl_xor(vals[v], off, 64);

  if (lane == 0) {
#pragma unroll
    for (int s = 0; s < 3; ++s) {
      const float inv = 1.f / vals[4*s + 3];    // self always selected -> n >= 1
      xci[(size_t)wid * 3 + s] =
          make_float4(vals[4*s] * inv, vals[4*s+1] * inv, vals[4*s+2] * inv, 0.f);
    }
    tau3[wid] = t3;
  }
}

// Kernel B (fast): one wave per point, lane L handles neighbor slot L.
__global__ __launch_bounds__(256) void kernelB_fast(
    const float4* __restrict__ xci, const float* __restrict__ wlin,
    const float* __restrict__ blin, const u16* __restrict__ nbr,
    float* __restrict__ out) {
  const int wid  = (blockIdx.x * 256 + threadIdx.x) >> 6;  // global point id
  const int lane = threadIdx.x & 63;
  const int pbase = wid & ~(MPTS - 1);                     // batch start

  const u16 e = nbr[(size_t)wid * KMAX + lane];
  const int cl = e >> 11;
  const int gj = pbase + (e & (MPTS - 1));

  const float4 ci0 = xci[(size_t)wid*3 + 0];
  const float4 ci1 = xci[(size_t)wid*3 + 1];
  const float4 ci2 = xci[(size_t)wid*3 + 2];

  float s0 = 0.f, s1 = 0.f, s2 = 0.f, n0 = 0.f, n1 = 0.f, n2 = 0.f;
  if (cl <= 2) {
    const float4 cj2 = xci[(size_t)gj*3 + 2];
    float ux = ci2.x - cj2.x, uy = ci2.y - cj2.y, uz = ci2.z - cj2.z;
    s2 = sqrtf(fmaxf(ux*ux + uy*uy + uz*uz, 1e-12f)); n2 = 1.f;
    if (cl <= 1) {
      const float4 cj1 = xci[(size_t)gj*3 + 1];
      ux = ci1.x - cj1.x; uy = ci1.y - cj1.y; uz = ci1.z - cj1.z;
      s1 = sqrtf(fmaxf(ux*ux + uy*uy + uz*uz, 1e-12f)); n1 = 1.f;
      if (cl == 0) {
        const float4 cj0 = xci[(size_t)gj*3 + 0];
        ux = ci0.x - cj0.x; uy = ci0.y - cj0.y; uz = ci0.z - cj0.z;
        s0 = sqrtf(fmaxf(ux*ux + uy*uy + uz*uz, 1e-12f)); n0 = 1.f;
      }
    }
  }

  float vals[6] = {s0, s1, s2, n0, n1, n2};
#pragma unroll
  for (int v = 0; v < 6; ++v)
#pragma unroll
    for (int off = 32; off > 0; off >>= 1)
      vals[v] += __shfl_xor(vals[v], off, 64);

  if (lane == 0) {
    const float msg0 = vals[0] / vals[3];
    const float msg1 = vals[1] / vals[4];
    const float msg2 = vals[2] / vals[5];
    const float z = wlin[0]*msg0 + wlin[1]*msg1 + wlin[2]*msg2 + blin[0];
    out[wid] = 1.f / (1.f + expf(-z));
  }
}

// Kernel B (fallback, ws too small): full scan with tau3 thresholds.
__global__ __launch_bounds__(256) void kernelB_slow(
    const float* __restrict__ pos, const float* __restrict__ wlin,
    const float* __restrict__ blin, const float4* __restrict__ xci,
    const float* __restrict__ tau3, float* __restrict__ out) {
  const int wid  = (blockIdx.x * 256 + threadIdx.x) >> 6;
  const int lane = threadIdx.x & 63;
  const int b = wid >> 11;
  const int i = wid & (MPTS - 1);
  const float* posb = pos + b * MPTS * 3;
  const int pbase = b * MPTS;

  const float pix = posb[3*i+0], piy = posb[3*i+1], piz = posb[3*i+2];
  const float t3 = tau3[wid];
  const float thr0 = fminf(0.01f, t3);
  const float thr1 = fminf(0.04f, t3);

  const float4 ci0 = xci[(size_t)wid*3 + 0];
  const float4 ci1 = xci[(size_t)wid*3 + 1];
  const float4 ci2 = xci[(size_t)wid*3 + 2];

  float s0=0.f, s1=0.f, s2=0.f, n0=0.f, n1=0.f, n2=0.f;
  for (int k = 0; k < NT; ++k) {
    const int j = k * 64 + lane;
    const float dx = posb[3*j+0] - pix;
    const float dy = posb[3*j+1] - piy;
    const float dz = posb[3*j+2] - piz;
    const float a3 = dx*dx + dy*dy + dz*dz;
    if (a3 <= t3) {
      const float4 cj2 = xci[(size_t)(pbase + j)*3 + 2];
      float ux = ci2.x-cj2.x, uy = ci2.y-cj2.y, uz = ci2.z-cj2.z;
      s2 += sqrtf(fmaxf(ux*ux+uy*uy+uz*uz, 1e-12f)); n2 += 1.f;
      if (a3 <= thr1) {
        const float4 cj1 = xci[(size_t)(pbase + j)*3 + 1];
        ux = ci1.x-cj1.x; uy = ci1.y-cj1.y; uz = ci1.z-cj1.z;
        s1 += sqrtf(fmaxf(ux*ux+uy*uy+uz*uz, 1e-12f)); n1 += 1.f;
        if (a3 <= thr0) {
          const float4 cj0 = xci[(size_t)(pbase + j)*3 + 0];
          ux = ci0.x-cj0.x; uy = ci0.y-cj0.y; uz = ci0.z-cj0.z;
          s0 += sqrtf(fmaxf(ux*ux+uy*uy+uz*uz, 1e-12f)); n0 += 1.f;
        }
      }
    }
  }

  float vals[6] = {s0, s1, s2, n0, n1, n2};
#pragma unroll
  for (int v = 0; v < 6; ++v)
#pragma unroll
    for (int off = 32; off > 0; off >>= 1)
      vals[v] += __shfl_xor(vals[v], off, 64);

  if (lane == 0) {
    const float msg0 = vals[0] / vals[3];
    const float msg1 = vals[1] / vals[4];
    const float msg2 = vals[2] / vals[5];
    const float z = wlin[0]*msg0 + wlin[1]*msg1 + wlin[2]*msg2 + blin[0];
    out[wid] = 1.f / (1.f + expf(-z));
  }
}

extern "C" void kernel_launch(void* const* d_in, const int* in_sizes, int n_in,
                              void* d_out, int out_size, void* d_ws, size_t ws_size,
                              hipStream_t stream) {
  (void)in_sizes; (void)n_in; (void)out_size;
  const float* x    = (const float*)d_in[0];   // [8,2048,3]
  const float* pos  = (const float*)d_in[1];   // [8,2048,3]
  const float* wlin = (const float*)d_in[2];   // [1,3]
  const float* blin = (const float*)d_in[3];   // [1]
  float* out = (float*)d_out;

  const size_t npts = (size_t)NBATCH * MPTS;
  const size_t xci_bytes = npts * 3 * sizeof(float4);   // 786,432
  const size_t tau_bytes = npts * sizeof(float);        //  65,536
  const size_t nbr_bytes = npts * KMAX * sizeof(u16);   // 2,097,152
  float4* xci = (float4*)d_ws;
  float* tau3 = (float*)((char*)d_ws + xci_bytes);
  u16* nbr    = (u16*)((char*)d_ws + xci_bytes + tau_bytes);
  const bool fast = ws_size >= xci_bytes + tau_bytes + nbr_bytes;

  const int nblocksA = (int)(npts / (TPB / 64));   // 8 points per block
  const int nblocksB = (int)(npts * 64 / 256);
  if (fast) {
    kernelA<true><<<nblocksA, TPB, 0, stream>>>(x, pos, xci, tau3, nbr);
    kernelB_fast<<<nblocksB, 256, 0, stream>>>(xci, wlin, blin, nbr, out);
  } else {
    kernelA<false><<<nblocksA, TPB, 0, stream>>>(x, pos, xci, tau3, nbr);
    kernelB_slow<<<nblocksB, 256, 0, stream>>>(pos, wlin, blin, xci, tau3, out);
  }
}

// Round 9
// 89.054 us; speedup vs baseline: 4.2818x; 1.0415x over previous
//
#include <hip/hip_runtime.h>
#include <math.h>

#define MPTS 2048
#define NBATCH 8
#define NT 32            // MPTS / 64 candidates per lane
#define KMAX 64
#define NBIN 128
#define BCAP 24          // rank-bin capture capacity (overflow -> bisect)
#define TPB 512          // 8 waves = 4 points x 2 metrics

typedef unsigned short u16;
typedef unsigned int u32;
typedef unsigned long long u64;

static __device__ __forceinline__ int mbcnt64(u64 m) {
  return __builtin_amdgcn_mbcnt_hi((u32)(m >> 32),
                                   __builtin_amdgcn_mbcnt_lo((u32)m, 0));
}

// Kernel A, metric-split: wave = (point, metric). metric 0: tau3 + 3D nbr list;
// metric 1: tau6 + x_centers (3 scales). Whole batch staged in LDS; exact
// top-64 threshold via per-wave 128-bin LDS histogram + rank-select.
// After the scan the wave's histogram region is reused for bcnt/bv/lst
// (same-wave DS ops are in-order; no barrier needed).
template <bool COMPACT>
__global__ __launch_bounds__(TPB, 6) void kernelA(
    const float* __restrict__ x, const float* __restrict__ pos,
    float4* __restrict__ xci, float* __restrict__ tau3, u16* __restrict__ nbr) {
  __shared__ __align__(16) float4 P4[MPTS];     // 32 KB (pos.xyz, x.x)
  __shared__ __align__(16) float2 X2[MPTS];     // 16 KB (x.y, x.z)
  __shared__ __align__(16) u32 histAll[8 * NBIN];  // 4 KB
  // per-wave region reuse after scan: hw[0]=bcnt, hw[1..24]=bv, hw[25..56]=lst

  const int tid  = threadIdx.x;
  const int wv   = tid >> 6;
  const int lane = tid & 63;
  const int pt   = wv >> 1;          // 0..3
  const int mtr  = wv & 1;           // 0 = 3D, 1 = 6D
  const int wid  = blockIdx.x * 4 + pt;        // global point id
  const int b    = wid >> 11;
  const int i    = wid & (MPTS - 1);
  const float* posb = pos + b * MPTS * 3;
  const float* xb   = x   + b * MPTS * 3;

  // cooperative stage of the whole batch
  for (int p = tid; p < MPTS; p += TPB) {
    P4[p] = make_float4(posb[3*p+0], posb[3*p+1], posb[3*p+2], xb[3*p+0]);
    X2[p] = make_float2(xb[3*p+1], xb[3*p+2]);
  }
  ((uint2*)histAll)[tid] = make_uint2(0u, 0u);   // zero all 8*128 bins
  __syncthreads();

  u32* hw = &histAll[wv * NBIN];                 // per-wave private

  const float4 pi4 = P4[i];
  const float2 xi2 = X2[i];

  const float R2 = mtr ? 0.2025f : 0.16f;
  const float SC = mtr ? (128.0f / 0.2025f) : (128.0f / 0.16f);

  // --- pass 1: distances (registers) + per-wave histogram (metric-specialized)
  float da[NT];
  if (mtr == 0) {
#pragma unroll
    for (int k = 0; k < NT; ++k) {
      const int j = k * 64 + lane;
      const float4 pj = P4[j];
      const float dx = pj.x - pi4.x, dy = pj.y - pi4.y, dz = pj.z - pi4.z;
      const float a = dx*dx + dy*dy + dz*dz;
      da[k] = a;
      if (a <= 0.16f) {
        int bb = (int)(a * (128.0f / 0.16f)); bb = bb > 127 ? 127 : bb;
        atomicAdd(&hw[bb], 1u);
      }
    }
  } else {
#pragma unroll
    for (int k = 0; k < NT; ++k) {
      const int j = k * 64 + lane;
      const float4 pj = P4[j];
      const float2 xj = X2[j];
      const float dx = pj.x - pi4.x, dy = pj.y - pi4.y, dz = pj.z - pi4.z;
      const float ex = pj.w - pi4.w, ey = xj.x - xi2.x, ez = xj.y - xi2.y;
      const float a = dx*dx + dy*dy + dz*dz + ex*ex + ey*ey + ez*ez;
      da[k] = a;
      if (a <= 0.2025f) {
        int bb = (int)(a * (128.0f / 0.2025f)); bb = bb > 127 ? 127 : bb;
        atomicAdd(&hw[bb], 1u);
      }
    }
  }

  // --- scan: lane owns bins 2*lane, 2*lane+1 (own wave's atomics: in-order)
  const u32 h0 = hw[2*lane], h1 = hw[2*lane+1];
  const u32 s2 = h0 + h1;
  u32 incl = s2;
#pragma unroll
  for (int off = 1; off < 64; off <<= 1) {
    const u32 tt = __shfl_up(incl, off, 64);
    if (lane >= off) incl += tt;
  }
  const u32 tot = __shfl(incl, 63, 64);
  float t = R2;

  if (tot > 64u) {
    const u32 excl = incl - s2;
    const u64 m = __ballot((excl < 64u) && (incl >= 64u));
    const int L = __builtin_ctzll(m);
    const u32 c0 = __shfl(excl, L, 64);
    const u32 g0 = __shfl(h0, L, 64);
    const u32 g1 = __shfl(h1, L, 64);
    int B; u32 cb, n;
    if (c0 + g0 >= 64u) { B = 2*L;     cb = c0;      n = g0; }
    else                { B = 2*L + 1; cb = c0 + g0; n = g1; }

    // hist region now dead -> reuse: hw[0]=bcnt, hw[1..]=bv
    if (lane == 0) hw[0] = 0u;
    float* bv = (float*)&hw[1];

    // compact bin-B members (expected 3-8, <=BCAP with huge margin)
#pragma unroll
    for (int k = 0; k < NT; ++k) {
      int bb = (int)(da[k] * SC); bb = bb > 127 ? 127 : bb;
      if ((da[k] <= R2) && (bb == B)) {
        const u32 s = atomicAdd(&hw[0], 1u);
        if (s < (u32)BCAP) bv[s] = da[k];
      }
    }

    if (n <= (u32)BCAP) {
      // stable rank-select the (64-cb)-th smallest (value-deterministic)
      const int nn = (int)n;
      const float v = (lane < nn) ? bv[lane] : 3.0e38f;
      u32 rank = 0;
      for (int cc = 0; cc < nn; ++cc) {
        const float w = __shfl(v, cc, 64);
        rank += ((w < v) || (w == v && cc < lane)) ? 1u : 0u;
      }
      const u64 sm = __ballot((lane < nn) && (rank == (u32)(63 - (int)cb)));
      t = __shfl(v, __builtin_ctzll(sm), 64);
    } else {
      // bisect fallback within bin B (~never)
      float lo = (float)B * (R2 / (float)NBIN), hi = lo + R2 / (float)NBIN;
      for (int it = 0; it < 26; ++it) {
        const float mid = 0.5f * (lo + hi);
        int c = 0;
#pragma unroll
        for (int k = 0; k < NT; ++k) c += __popcll(__ballot(da[k] <= mid));
        if (c >= 64) { hi = mid; if (c == 64) break; } else lo = mid;
      }
      t = hi;
    }
  }

  // --- pass 2: ballot-compact the selected set (<=64, index-ordered = stable)
  u16* lw = (u16*)&hw[1 + BCAP];     // 64 x u16 in reused hist space
  const float q0 = mtr ? 0.0225f : 0.01f;
  const float q1 = mtr ? 0.0625f : 0.04f;
  int base = 0;
#pragma unroll
  for (int k = 0; k < NT; ++k) {
    const int j = k * 64 + lane;
    const bool sel = (da[k] <= t);
    const u64 m = __ballot(sel);
    const int s = base + mbcnt64(m);
    if (sel && s < KMAX) {
      const int cl = (da[k] > q0) + (da[k] > q1);
      lw[s] = (u16)(j | (cl << 11));
    }
    base += __popcll(m);
  }
  const int cn = base < KMAX ? base : KMAX;

  if (mtr == 0) {
    // 3D: neighbor list -> global (coalesced), tau3 for the fallback path
    if (COMPACT)
      nbr[(size_t)wid * KMAX + lane] = (lane < cn) ? lw[lane] : (u16)(3u << 11);
    if (lane == 0) tau3[wid] = t;
  } else {
    // 6D: masked means -> x_centers, one gather + predication + reduce
    const u16 e = (lane < cn) ? lw[lane] : (u16)0xFFFF;   // cl=3 pad
    const int cl = (e >> 11) & 3;
    const int jj = e & (MPTS - 1);
    const float xjx = P4[jj].w;
    const float2 xj = X2[jj];
    const bool v2 = (cl <= 2), v1 = (cl <= 1), v0 = (cl == 0);

    float vals[12];
    vals[0] = v0 ? xjx : 0.f; vals[1] = v0 ? xj.x : 0.f; vals[2]  = v0 ? xj.y : 0.f; vals[3]  = v0 ? 1.f : 0.f;
    vals[4] = v1 ? xjx : 0.f; vals[5] = v1 ? xj.x : 0.f; vals[6]  = v1 ? xj.y : 0.f; vals[7]  = v1 ? 1.f : 0.f;
    vals[8] = v2 ? xjx : 0.f; vals[9] = v2 ? xj.x : 0.f; vals[10] = v2 ? xj.y : 0.f; vals[11] = v2 ? 1.f : 0.f;

#pragma unroll
    for (int v = 0; v < 12; ++v)
#pragma unroll
      for (int off = 32; off > 0; off >>= 1)
        vals[v] += __shfl_xor(vals[v], off, 64);

    if (lane == 0) {
#pragma unroll
      for (int s = 0; s < 3; ++s) {
        const float inv = 1.f / vals[4*s + 3];   // self always selected -> n >= 1
        xci[(size_t)wid * 3 + s] =
            make_float4(vals[4*s] * inv, vals[4*s+1] * inv, vals[4*s+2] * inv, 0.f);
      }
    }
  }
}

// Kernel B (fast): one wave per point, lane L handles neighbor slot L.
__global__ __launch_bounds__(256) void kernelB_fast(
    const float4* __restrict__ xci, const float* __restrict__ wlin,
    const float* __restrict__ blin, const u16* __restrict__ nbr,
    float* __restrict__ out) {
  const int wid  = (blockIdx.x * 256 + threadIdx.x) >> 6;  // global point id
  const int lane = threadIdx.x & 63;
  const int pbase = wid & ~(MPTS - 1);                     // batch start

  const u16 e = nbr[(size_t)wid * KMAX + lane];
  const int cl = e >> 11;
  const int gj = pbase + (e & (MPTS - 1));

  const float4 ci0 = xci[(size_t)wid*3 + 0];
  const float4 ci1 = xci[(size_t)wid*3 + 1];
  const float4 ci2 = xci[(size_t)wid*3 + 2];

  float s0 = 0.f, s1 = 0.f, s2 = 0.f, n0 = 0.f, n1 = 0.f, n2 = 0.f;
  if (cl <= 2) {
    const float4 cj2 = xci[(size_t)gj*3 + 2];
    float ux = ci2.x - cj2.x, uy = ci2.y - cj2.y, uz = ci2.z - cj2.z;
    s2 = sqrtf(fmaxf(ux*ux + uy*uy + uz*uz, 1e-12f)); n2 = 1.f;
    if (cl <= 1) {
      const float4 cj1 = xci[(size_t)gj*3 + 1];
      ux = ci1.x - cj1.x; uy = ci1.y - cj1.y; uz = ci1.z - cj1.z;
      s1 = sqrtf(fmaxf(ux*ux + uy*uy + uz*uz, 1e-12f)); n1 = 1.f;
      if (cl == 0) {
        const float4 cj0 = xci[(size_t)gj*3 + 0];
        ux = ci0.x - cj0.x; uy = ci0.y - cj0.y; uz = ci0.z - cj0.z;
        s0 = sqrtf(fmaxf(ux*ux + uy*uy + uz*uz, 1e-12f)); n0 = 1.f;
      }
    }
  }

  float vals[6] = {s0, s1, s2, n0, n1, n2};
#pragma unroll
  for (int v = 0; v < 6; ++v)
#pragma unroll
    for (int off = 32; off > 0; off >>= 1)
      vals[v] += __shfl_xor(vals[v], off, 64);

  if (lane == 0) {
    const float msg0 = vals[0] / vals[3];
    const float msg1 = vals[1] / vals[4];
    const float msg2 = vals[2] / vals[5];
    const float z = wlin[0]*msg0 + wlin[1]*msg1 + wlin[2]*msg2 + blin[0];
    out[wid] = 1.f / (1.f + expf(-z));
  }
}

// Kernel B (fallback, ws too small): full scan with tau3 thresholds.
__global__ __launch_bounds__(256) void kernelB_slow(
    const float* __restrict__ pos, const float* __restrict__ wlin,
    const float* __restrict__ blin, const float4* __restrict__ xci,
    const float* __restrict__ tau3, float* __restrict__ out) {
  const int wid  = (blockIdx.x * 256 + threadIdx.x) >> 6;
  const int lane = threadIdx.x & 63;
  const int b = wid >> 11;
  const int i = wid & (MPTS - 1);
  const float* posb = pos + b * MPTS * 3;
  const int pbase = b * MPTS;

  const float pix = posb[3*i+0], piy = posb[3*i+1], piz = posb[3*i+2];
  const float t3 = tau3[wid];
  const float thr0 = fminf(0.01f, t3);
  const float thr1 = fminf(0.04f, t3);

  const float4 ci0 = xci[(size_t)wid*3 + 0];
  const float4 ci1 = xci[(size_t)wid*3 + 1];
  const float4 ci2 = xci[(size_t)wid*3 + 2];

  float s0=0.f, s1=0.f, s2=0.f, n0=0.f, n1=0.f, n2=0.f;
  for (int k = 0; k < NT; ++k) {
    const int j = k * 64 + lane;
    const float dx = posb[3*j+0] - pix;
    const float dy = posb[3*j+1] - piy;
    const float dz = posb[3*j+2] - piz;
    const float a3 = dx*dx + dy*dy + dz*dz;
    if (a3 <= t3) {
      const float4 cj2 = xci[(size_t)(pbase + j)*3 + 2];
      float ux = ci2.x-cj2.x, uy = ci2.y-cj2.y, uz = ci2.z-cj2.z;
      s2 += sqrtf(fmaxf(ux*ux+uy*uy+uz*uz, 1e-12f)); n2 += 1.f;
      if (a3 <= thr1) {
        const float4 cj1 = xci[(size_t)(pbase + j)*3 + 1];
        ux = ci1.x-cj1.x; uy = ci1.y-cj1.y; uz = ci1.z-cj1.z;
        s1 += sqrtf(fmaxf(ux*ux+uy*uy+uz*uz, 1e-12f)); n1 += 1.f;
        if (a3 <= thr0) {
          const float4 cj0 = xci[(size_t)(pbase + j)*3 + 0];
          ux = ci0.x-cj0.x; uy = ci0.y-cj0.y; uz = ci0.z-cj0.z;
          s0 += sqrtf(fmaxf(ux*ux+uy*uy+uz*uz, 1e-12f)); n0 += 1.f;
        }
      }
    }
  }

  float vals[6] = {s0, s1, s2, n0, n1, n2};
#pragma unroll
  for (int v = 0; v < 6; ++v)
#pragma unroll
    for (int off = 32; off > 0; off >>= 1)
      vals[v] += __shfl_xor(vals[v], off, 64);

  if (lane == 0) {
    const float msg0 = vals[0] / vals[3];
    const float msg1 = vals[1] / vals[4];
    const float msg2 = vals[2] / vals[5];
    const float z = wlin[0]*msg0 + wlin[1]*msg1 + wlin[2]*msg2 + blin[0];
    out[wid] = 1.f / (1.f + expf(-z));
  }
}

extern "C" void kernel_launch(void* const* d_in, const int* in_sizes, int n_in,
                              void* d_out, int out_size, void* d_ws, size_t ws_size,
                              hipStream_t stream) {
  (void)in_sizes; (void)n_in; (void)out_size;
  const float* x    = (const float*)d_in[0];   // [8,2048,3]
  const float* pos  = (const float*)d_in[1];   // [8,2048,3]
  const float* wlin = (const float*)d_in[2];   // [1,3]
  const float* blin = (const float*)d_in[3];   // [1]
  float* out = (float*)d_out;

  const size_t npts = (size_t)NBATCH * MPTS;
  const size_t xci_bytes = npts * 3 * sizeof(float4);   // 786,432
  const size_t tau_bytes = npts * sizeof(float);        //  65,536
  const size_t nbr_bytes = npts * KMAX * sizeof(u16);   // 2,097,152
  float4* xci = (float4*)d_ws;
  float* tau3 = (float*)((char*)d_ws + xci_bytes);
  u16* nbr    = (u16*)((char*)d_ws + xci_bytes + tau_bytes);
  const bool fast = ws_size >= xci_bytes + tau_bytes + nbr_bytes;

  const int nblocksA = (int)(npts / 4);            // 4 points x 2 metric-waves
  const int nblocksB = (int)(npts * 64 / 256);
  if (fast) {
    kernelA<true><<<nblocksA, TPB, 0, stream>>>(x, pos, xci, tau3, nbr);
    kernelB_fast<<<nblocksB, 256, 0, stream>>>(xci, wlin, blin, nbr, out);
  } else {
    kernelA<false><<<nblocksA, TPB, 0, stream>>>(x, pos, xci, tau3, nbr);
    kernelB_slow<<<nblocksB, 256, 0, stream>>>(pos, wlin, blin, xci, tau3, out);
  }
}

// Round 10
// 83.713 us; speedup vs baseline: 4.5550x; 1.0638x over previous
//
#include <hip/hip_runtime.h>
#include <math.h>

#define MPTS 2048
#define NBATCH 8
#define NT 32            // MPTS / 64 candidates per lane
#define KMAX 64
#define NBIN 128
#define BCAP 24          // rank-bin capture capacity (overflow -> bisect)
#define TPB 512          // 8 waves = 4 points x 2 metrics

typedef unsigned short u16;
typedef unsigned int u32;
typedef unsigned long long u64;

static __device__ __forceinline__ int mbcnt64(u64 m) {
  return __builtin_amdgcn_mbcnt_hi((u32)(m >> 32),
                                   __builtin_amdgcn_mbcnt_lo((u32)m, 0));
}

// Kernel A, metric-split: wave = (point, metric). metric 0: tau3 + 3D nbr list;
// metric 1: tau6 + x_centers (3 scales). Whole batch staged in LDS; exact
// top-64 threshold via per-wave 128-bin LDS histogram + rank-select.
// Distances use packed-fp32 (float2 -> v_pk_*) math.
template <bool COMPACT>
__global__ __launch_bounds__(TPB, 6) void kernelA(
    const float* __restrict__ x, const float* __restrict__ pos,
    float4* __restrict__ xci, float* __restrict__ tau3, u16* __restrict__ nbr) {
  __shared__ __align__(16) float4 P4[MPTS];        // 32 KB (pos.xyz, x.x)
  __shared__ __align__(16) float2 X2[MPTS];        // 16 KB (x.y, x.z)
  __shared__ __align__(16) u32 histAll[8 * NBIN];  // 4 KB
  // per-wave region reuse after scan: hw[0]=bcnt, hw[1..BCAP]=bv, then lst

  const int tid  = threadIdx.x;
  const int wv   = tid >> 6;
  const int lane = tid & 63;
  const int pt   = wv >> 1;          // 0..3
  const int mtr  = wv & 1;           // 0 = 3D, 1 = 6D
  const int wid  = blockIdx.x * 4 + pt;        // global point id
  const int b    = wid >> 11;
  const int i    = wid & (MPTS - 1);
  const float* posb = pos + b * MPTS * 3;
  const float* xb   = x   + b * MPTS * 3;

  // cooperative stage of the whole batch
  for (int p = tid; p < MPTS; p += TPB) {
    P4[p] = make_float4(posb[3*p+0], posb[3*p+1], posb[3*p+2], xb[3*p+0]);
    X2[p] = make_float2(xb[3*p+1], xb[3*p+2]);
  }
  ((uint2*)histAll)[tid] = make_uint2(0u, 0u);   // zero all 8*128 bins
  __syncthreads();

  u32* hw = &histAll[wv * NBIN];                 // per-wave private

  const float4 pi4 = P4[i];
  const float2 xi2 = X2[i];
  const float2 c0 = make_float2(pi4.x, pi4.y);   // (pix, piy)
  const float2 c1 = make_float2(pi4.z, pi4.w);   // (piz, xix)
  const float2 c2 = xi2;                          // (xiy, xiz)

  const float R2 = mtr ? 0.2025f : 0.16f;
  const float SC = mtr ? (128.0f / 0.2025f) : (128.0f / 0.16f);

  // --- pass 1: distances (registers, packed math) + per-wave histogram
  float da[NT];
  if (mtr == 0) {
#pragma unroll
    for (int k = 0; k < NT; ++k) {
      const int j = k * 64 + lane;
      const float4 pj = P4[j];
      const float2 d01 = make_float2(pj.x, pj.y) - c0;   // pk_sub
      const float dz = pj.z - pi4.z;
      const float2 sq = d01 * d01;                        // pk_mul
      const float a = sq.x + sq.y + dz * dz;
      da[k] = a;
      const int bb = (int)(a * (128.0f / 0.16f));
      if ((u32)bb < 128u) atomicAdd(&hw[bb], 1u);
    }
  } else {
#pragma unroll
    for (int k = 0; k < NT; ++k) {
      const int j = k * 64 + lane;
      const float4 pj = P4[j];
      const float2 xj = X2[j];
      const float2 a0 = make_float2(pj.x, pj.y) - c0;    // pk_sub
      const float2 a1 = make_float2(pj.z, pj.w) - c1;    // pk_sub
      const float2 a2 = xj - c2;                          // pk_sub
      float2 s = a0 * a0;                                 // pk_mul
      s += a1 * a1;                                       // pk_fma
      s += a2 * a2;                                       // pk_fma
      const float a = s.x + s.y;
      da[k] = a;
      const int bb = (int)(a * (128.0f / 0.2025f));
      if ((u32)bb < 128u) atomicAdd(&hw[bb], 1u);
    }
  }

  // --- scan: lane owns bins 2*lane, 2*lane+1 (own wave's atomics: in-order)
  const u32 h0 = hw[2*lane], h1 = hw[2*lane+1];
  const u32 s2 = h0 + h1;
  u32 incl = s2;
#pragma unroll
  for (int off = 1; off < 64; off <<= 1) {
    const u32 tt = __shfl_up(incl, off, 64);
    if (lane >= off) incl += tt;
  }
  const u32 tot = __shfl(incl, 63, 64);
  float t = R2;

  if (tot > 64u) {
    const u32 excl = incl - s2;
    const u64 m = __ballot((excl < 64u) && (incl >= 64u));
    const int L = __builtin_ctzll(m);
    const u32 c0b = __shfl(excl, L, 64);
    const u32 g0 = __shfl(h0, L, 64);
    const u32 g1 = __shfl(h1, L, 64);
    int B; u32 cb, n;
    if (c0b + g0 >= 64u) { B = 2*L;     cb = c0b;      n = g0; }
    else                 { B = 2*L + 1; cb = c0b + g0; n = g1; }

    // hist region now dead -> reuse: hw[0]=bcnt, hw[1..]=bv
    if (lane == 0) hw[0] = 0u;
    float* bv = (float*)&hw[1];

    // compact bin-B members (expected 1-8, <=BCAP with huge margin)
#pragma unroll
    for (int k = 0; k < NT; ++k) {
      const int bb = (int)(da[k] * SC);
      if (bb == B) {
        const u32 s = atomicAdd(&hw[0], 1u);
        if (s < (u32)BCAP) bv[s] = da[k];
      }
    }

    if (n <= (u32)BCAP) {
      // stable rank-select the (64-cb)-th smallest (value-deterministic)
      const int nn = (int)n;
      const float v = (lane < nn) ? bv[lane] : 3.0e38f;
      u32 rank = 0;
      for (int cc = 0; cc < nn; ++cc) {
        const float w = __shfl(v, cc, 64);
        rank += ((w < v) || (w == v && cc < lane)) ? 1u : 0u;
      }
      const u64 sm = __ballot((lane < nn) && (rank == (u32)(63 - (int)cb)));
      t = __shfl(v, __builtin_ctzll(sm), 64);
    } else {
      // bisect fallback within bin B (~never)
      float lo = (float)B * (R2 / (float)NBIN), hi = lo + R2 / (float)NBIN;
      for (int it = 0; it < 26; ++it) {
        const float mid = 0.5f * (lo + hi);
        int c = 0;
#pragma unroll
        for (int k = 0; k < NT; ++k) c += __popcll(__ballot(da[k] <= mid));
        if (c >= 64) { hi = mid; if (c == 64) break; } else lo = mid;
      }
      t = hi;
    }
  }

  // --- pass 2: ballot-compact the selected set (<=64, index-ordered = stable)
  u16* lw = (u16*)&hw[1 + BCAP];     // 64 x u16 in reused hist space
  const float q0 = mtr ? 0.0225f : 0.01f;
  const float q1 = mtr ? 0.0625f : 0.04f;
  int base = 0;
#pragma unroll
  for (int k = 0; k < NT; ++k) {
    const int j = k * 64 + lane;
    const bool sel = (da[k] <= t);
    const u64 m = __ballot(sel);
    const int s = base + mbcnt64(m);
    if (sel && s < KMAX) {
      const int cl = (da[k] > q0) + (da[k] > q1);
      lw[s] = (u16)(j | (cl << 11));
    }
    base += __popcll(m);
  }
  const int cn = base < KMAX ? base : KMAX;

  if (mtr == 0) {
    // 3D: neighbor list -> global (coalesced), tau3 for the fallback path
    if (COMPACT)
      nbr[(size_t)wid * KMAX + lane] = (lane < cn) ? lw[lane] : (u16)(3u << 11);
    if (lane == 0) tau3[wid] = t;
  } else {
    // 6D: masked means -> x_centers, one gather + predication + packed reduce
    const u16 e = (lane < cn) ? lw[lane] : (u16)0xFFFF;   // cl=3 pad
    const int cl = (e >> 11) & 3;
    const int jj = e & (MPTS - 1);
    const float xjx = P4[jj].w;
    const float2 xj = X2[jj];
    const bool v2 = (cl <= 2), v1 = (cl <= 1), v0 = (cl == 0);

    // 6 float2 accumulators: per scale {(sx,sy),(sz,n)}
    float2 v2a[6];
    v2a[0] = v0 ? make_float2(xjx, xj.x) : make_float2(0.f, 0.f);
    v2a[1] = v0 ? make_float2(xj.y, 1.f) : make_float2(0.f, 0.f);
    v2a[2] = v1 ? make_float2(xjx, xj.x) : make_float2(0.f, 0.f);
    v2a[3] = v1 ? make_float2(xj.y, 1.f) : make_float2(0.f, 0.f);
    v2a[4] = v2 ? make_float2(xjx, xj.x) : make_float2(0.f, 0.f);
    v2a[5] = v2 ? make_float2(xj.y, 1.f) : make_float2(0.f, 0.f);

#pragma unroll
    for (int v = 0; v < 6; ++v)
#pragma unroll
      for (int off = 32; off > 0; off >>= 1) {
        float2 o;
        o.x = __shfl_xor(v2a[v].x, off, 64);
        o.y = __shfl_xor(v2a[v].y, off, 64);
        v2a[v] += o;                                      // pk_add
      }

    if (lane == 0) {
#pragma unroll
      for (int s = 0; s < 3; ++s) {
        const float inv = 1.f / v2a[2*s+1].y;   // self always selected -> n >= 1
        xci[(size_t)wid * 3 + s] =
            make_float4(v2a[2*s].x * inv, v2a[2*s].y * inv, v2a[2*s+1].x * inv, 0.f);
      }
    }
  }
}

// Kernel B (fast): one wave per point, lane L handles neighbor slot L.
__global__ __launch_bounds__(256) void kernelB_fast(
    const float4* __restrict__ xci, const float* __restrict__ wlin,
    const float* __restrict__ blin, const u16* __restrict__ nbr,
    float* __restrict__ out) {
  const int wid  = (blockIdx.x * 256 + threadIdx.x) >> 6;  // global point id
  const int lane = threadIdx.x & 63;
  const int pbase = wid & ~(MPTS - 1);                     // batch start

  const u16 e = nbr[(size_t)wid * KMAX + lane];
  const int cl = e >> 11;
  const int gj = pbase + (e & (MPTS - 1));

  const float4 ci0 = xci[(size_t)wid*3 + 0];
  const float4 ci1 = xci[(size_t)wid*3 + 1];
  const float4 ci2 = xci[(size_t)wid*3 + 2];

  float s0 = 0.f, s1 = 0.f, s2 = 0.f, n0 = 0.f, n1 = 0.f, n2 = 0.f;
  if (cl <= 2) {
    const float4 cj2 = xci[(size_t)gj*3 + 2];
    float ux = ci2.x - cj2.x, uy = ci2.y - cj2.y, uz = ci2.z - cj2.z;
    s2 = sqrtf(fmaxf(ux*ux + uy*uy + uz*uz, 1e-12f)); n2 = 1.f;
    if (cl <= 1) {
      const float4 cj1 = xci[(size_t)gj*3 + 1];
      ux = ci1.x - cj1.x; uy = ci1.y - cj1.y; uz = ci1.z - cj1.z;
      s1 = sqrtf(fmaxf(ux*ux + uy*uy + uz*uz, 1e-12f)); n1 = 1.f;
      if (cl == 0) {
        const float4 cj0 = xci[(size_t)gj*3 + 0];
        ux = ci0.x - cj0.x; uy = ci0.y - cj0.y; uz = ci0.z - cj0.z;
        s0 = sqrtf(fmaxf(ux*ux + uy*uy + uz*uz, 1e-12f)); n0 = 1.f;
      }
    }
  }

  float vals[6] = {s0, s1, s2, n0, n1, n2};
#pragma unroll
  for (int v = 0; v < 6; ++v)
#pragma unroll
    for (int off = 32; off > 0; off >>= 1)
      vals[v] += __shfl_xor(vals[v], off, 64);

  if (lane == 0) {
    const float msg0 = vals[0] / vals[3];
    const float msg1 = vals[1] / vals[4];
    const float msg2 = vals[2] / vals[5];
    const float z = wlin[0]*msg0 + wlin[1]*msg1 + wlin[2]*msg2 + blin[0];
    out[wid] = 1.f / (1.f + expf(-z));
  }
}

// Kernel B (fallback, ws too small): full scan with tau3 thresholds.
__global__ __launch_bounds__(256) void kernelB_slow(
    const float* __restrict__ pos, const float* __restrict__ wlin,
    const float* __restrict__ blin, const float4* __restrict__ xci,
    const float* __restrict__ tau3, float* __restrict__ out) {
  const int wid  = (blockIdx.x * 256 + threadIdx.x) >> 6;
  const int lane = threadIdx.x & 63;
  const int b = wid >> 11;
  const int i = wid & (MPTS - 1);
  const float* posb = pos + b * MPTS * 3;
  const int pbase = b * MPTS;

  const float pix = posb[3*i+0], piy = posb[3*i+1], piz = posb[3*i+2];
  const float t3 = tau3[wid];
  const float thr0 = fminf(0.01f, t3);
  const float thr1 = fminf(0.04f, t3);

  const float4 ci0 = xci[(size_t)wid*3 + 0];
  const float4 ci1 = xci[(size_t)wid*3 + 1];
  const float4 ci2 = xci[(size_t)wid*3 + 2];

  float s0=0.f, s1=0.f, s2=0.f, n0=0.f, n1=0.f, n2=0.f;
  for (int k = 0; k < NT; ++k) {
    const int j = k * 64 + lane;
    const float dx = posb[3*j+0] - pix;
    const float dy = posb[3*j+1] - piy;
    const float dz = posb[3*j+2] - piz;
    const float a3 = dx*dx + dy*dy + dz*dz;
    if (a3 <= t3) {
      const float4 cj2 = xci[(size_t)(pbase + j)*3 + 2];
      float ux = ci2.x-cj2.x, uy = ci2.y-cj2.y, uz = ci2.z-cj2.z;
      s2 += sqrtf(fmaxf(ux*ux+uy*uy+uz*uz, 1e-12f)); n2 += 1.f;
      if (a3 <= thr1) {
        const float4 cj1 = xci[(size_t)(pbase + j)*3 + 1];
        ux = ci1.x-cj1.x; uy = ci1.y-cj1.y; uz = ci1.z-cj1.z;
        s1 += sqrtf(fmaxf(ux*ux+uy*uy+uz*uz, 1e-12f)); n1 += 1.f;
        if (a3 <= thr0) {
          const float4 cj0 = xci[(size_t)(pbase + j)*3 + 0];
          ux = ci0.x-cj0.x; uy = ci0.y-cj0.y; uz = ci0.z-cj0.z;
          s0 += sqrtf(fmaxf(ux*ux+uy*uy+uz*uz, 1e-12f)); n0 += 1.f;
        }
      }
    }
  }

  float vals[6] = {s0, s1, s2, n0, n1, n2};
#pragma unroll
  for (int v = 0; v < 6; ++v)
#pragma unroll
    for (int off = 32; off > 0; off >>= 1)
      vals[v] += __shfl_xor(vals[v], off, 64);

  if (lane == 0) {
    const float msg0 = vals[0] / vals[3];
    const float msg1 = vals[1] / vals[4];
    const float msg2 = vals[2] / vals[5];
    const float z = wlin[0]*msg0 + wlin[1]*msg1 + wlin[2]*msg2 + blin[0];
    out[wid] = 1.f / (1.f + expf(-z));
  }
}

extern "C" void kernel_launch(void* const* d_in, const int* in_sizes, int n_in,
                              void* d_out, int out_size, void* d_ws, size_t ws_size,
                              hipStream_t stream) {
  (void)in_sizes; (void)n_in; (void)out_size;
  const float* x    = (const float*)d_in[0];   // [8,2048,3]
  const float* pos  = (const float*)d_in[1];   // [8,2048,3]
  const float* wlin = (const float*)d_in[2];   // [1,3]
  const float* blin = (const float*)d_in[3];   // [1]
  float* out = (float*)d_out;

  const size_t npts = (size_t)NBATCH * MPTS;
  const size_t xci_bytes = npts * 3 * sizeof(float4);   // 786,432
  const size_t tau_bytes = npts * sizeof(float);        //  65,536
  const size_t nbr_bytes = npts * KMAX * sizeof(u16);   // 2,097,152
  float4* xci = (float4*)d_ws;
  float* tau3 = (float*)((char*)d_ws + xci_bytes);
  u16* nbr    = (u16*)((char*)d_ws + xci_bytes + tau_bytes);
  const bool fast = ws_size >= xci_bytes + tau_bytes + nbr_bytes;

  const int nblocksA = (int)(npts / 4);            // 4 points x 2 metric-waves
  const int nblocksB = (int)(npts * 64 / 256);
  if (fast) {
    kernelA<true><<<nblocksA, TPB, 0, stream>>>(x, pos, xci, tau3, nbr);
    kernelB_fast<<<nblocksB, 256, 0, stream>>>(xci, wlin, blin, nbr, out);
  } else {
    kernelA<false><<<nblocksA, TPB, 0, stream>>>(x, pos, xci, tau3, nbr);
    kernelB_slow<<<nblocksB, 256, 0, stream>>>(pos, wlin, blin, xci, tau3, out);
  }
}